// Round 12
// baseline (290.506 us; speedup 1.0000x reference)
//
#include <hip/hip_runtime.h>
#include <hip/hip_fp16.h>

#define N_NODES  100000
#define N_EDGES  1000000
#define E_TOT    1100000   // edges + self-loops
#define E_CAP    1900000   // padded-CSR capacity (deg padded to x8: <= E_TOT + 7*N)
#define N_GRAPHS 64

typedef _Float16 half8 __attribute__((ext_vector_type(8)));
typedef float    f32x4 __attribute__((ext_vector_type(4)));

__device__ __forceinline__ float elu_f(float v) {
    return v > 0.f ? v : expm1f(v);
}

__device__ __forceinline__ float lrelu(float v) {
    return v > 0.f ? v : 0.2f * v;
}

// ---------------------------------------------------------------------------
// k_preall: block 0 = folded attention projections (exact algebra);
//           blocks 1..32 = fragment-ordered fp16 W2 for the MFMA B-operand.
// ---------------------------------------------------------------------------
__global__ void k_preall(const float* __restrict__ w1,
                         const float* __restrict__ as1v, const float* __restrict__ ad1v,
                         const float* __restrict__ w2,
                         const float* __restrict__ as2v, const float* __restrict__ ad2v,
                         float* __restrict__ A1, float* __restrict__ D1,
                         float* __restrict__ B2, float* __restrict__ E2,
                         __half* __restrict__ w2frag)
{
    if (blockIdx.x == 0) {
        int t = threadIdx.x;
        if (t < 128) {
            float acc = 0.f;
            for (int d = 0; d < 64; ++d) acc += w2[d * 128 + t] * as2v[d];
            B2[t] = acc;
        } else {
            int k = t - 128;
            float acc = 0.f;
            for (int d = 0; d < 64; ++d) acc += w2[d * 128 + k] * ad2v[d];
            E2[k] = acc;
        }
        if (t < 8) {
            int h = t >> 2, k = t & 3;
            float acc = 0.f;
            for (int d = 0; d < 64; ++d) acc += w1[(h * 64 + d) * 4 + k] * as1v[h * 64 + d];
            A1[t] = acc;
        } else if (t < 16) {
            int i = t - 8, h = i >> 2, k = i & 3;
            float acc = 0.f;
            for (int d = 0; d < 64; ++d) acc += w1[(h * 64 + d) * 4 + k] * ad1v[h * 64 + d];
            D1[i] = acc;
        }
    } else {
        int f = (blockIdx.x - 1) * 256 + threadIdx.x;  // 8192 total
        int j = f & 7, ln = (f >> 3) & 63, g = f >> 9; // g = nt*4+ks
        int nt = g >> 2, ks = g & 3;
        int col = nt * 16 + (ln & 15);
        int k   = ks * 32 + ((ln >> 4) << 3) + j;
        w2frag[f] = __float2half(w2[col * 128 + k]);
    }
}

// ---------------------------------------------------------------------------
// CSR build (padded to x8): histogram -> scan (writes rowptr + cursor copy)
// -> scatter via cursor atomics (no pos array)
// ---------------------------------------------------------------------------
__global__ void k_count(const int* __restrict__ ei, int* __restrict__ deg)
{
    int e = blockIdx.x * blockDim.x + threadIdx.x;
    if (e >= E_TOT) return;
    int dst = (e < N_EDGES) ? ei[N_EDGES + e] : (e - N_EDGES);
    atomicAdd(&deg[dst], 1);
}

__global__ void k_scan1(const int* __restrict__ deg, int* __restrict__ rowptr, int* __restrict__ bsum)
{
    __shared__ int sh[256];
    int tid = threadIdx.x;
    int i = blockIdx.x * 256 + tid;
    int v = (i <= N_NODES) ? ((deg[i] + 7) & ~7) : 0;
    int acc = v;
    sh[tid] = acc; __syncthreads();
    for (int off = 1; off < 256; off <<= 1) {
        int add = (tid >= off) ? sh[tid - off] : 0;
        __syncthreads();
        acc += add;
        sh[tid] = acc;
        __syncthreads();
    }
    if (i <= N_NODES) rowptr[i] = acc - v;
    if (tid == 255) bsum[blockIdx.x] = acc;
}

__global__ void k_scan2(int* __restrict__ bsum, int nb)
{
    __shared__ int sh[512];
    int tid = threadIdx.x;
    int v = (tid < nb) ? bsum[tid] : 0;
    int acc = v;
    sh[tid] = acc; __syncthreads();
    for (int off = 1; off < 512; off <<= 1) {
        int add = (tid >= off) ? sh[tid - off] : 0;
        __syncthreads();
        acc += add;
        sh[tid] = acc;
        __syncthreads();
    }
    if (tid < nb) bsum[tid] = acc - v;
}

__global__ void k_scan3(int* __restrict__ rowptr, int* __restrict__ cur, const int* __restrict__ bsum)
{
    int i = blockIdx.x * 256 + threadIdx.x;
    if (i <= N_NODES) {
        int v = rowptr[i] + bsum[blockIdx.x];
        rowptr[i] = v;
        if (i < N_NODES) cur[i] = v;
    }
}

__global__ void k_scatter(const int* __restrict__ ei, int* __restrict__ cur,
                          int* __restrict__ srcs)
{
    int e = blockIdx.x * blockDim.x + threadIdx.x;
    if (e >= E_TOT) return;
    int src = (e < N_EDGES) ? ei[e] : (e - N_EDGES);
    int dst = (e < N_EDGES) ? ei[N_EDGES + e] : (e - N_EDGES);
    int j = atomicAdd(&cur[dst], 1);
    srcs[j] = src;
}

// ---------------------------------------------------------------------------
// Layer-1 aggregation in x-space (16 lanes per node, one edge per lane)
// ---------------------------------------------------------------------------
__global__ void __launch_bounds__(256) k_gather1x(
    const int* __restrict__ srcs, const int* __restrict__ rowptr, const int* __restrict__ deg,
    const float* __restrict__ x,
    const float* __restrict__ A1c, const float* __restrict__ D1c,
    float4* __restrict__ agg0, float4* __restrict__ agg1, float2* __restrict__ wsA)
{
    const int tid  = threadIdx.x;
    const int n    = blockIdx.x * 16 + (tid >> 4);
    const int lane = tid & 15;
    if (n >= N_NODES) return;

    const float4 A0 = ((const float4*)A1c)[0], A1v = ((const float4*)A1c)[1];
    const float4 D0 = ((const float4*)D1c)[0], D1v = ((const float4*)D1c)[1];
    const float4 xn = ((const float4*)x)[n];
    const float ad0 = xn.x * D0.x + xn.y * D0.y + xn.z * D0.z + xn.w * D0.w;
    const float ad1 = xn.x * D1v.x + xn.y * D1v.y + xn.z * D1v.z + xn.w * D1v.w;

    const int beg = rowptr[n], rend = beg + deg[n];
    float4 acc0 = {0.f, 0.f, 0.f, 0.f}, acc1 = {0.f, 0.f, 0.f, 0.f};
    float ws0 = 0.f, ws1 = 0.f;
    for (int j = beg + lane; j < rend; j += 16) {
        const int s = srcs[j];
        const float4 xs = ((const float4*)x)[s];
        const float as0 = xs.x * A0.x + xs.y * A0.y + xs.z * A0.z + xs.w * A0.w;
        const float as1 = xs.x * A1v.x + xs.y * A1v.y + xs.z * A1v.z + xs.w * A1v.w;
        const float w0 = __expf(lrelu(as0 + ad0));
        const float w1 = __expf(lrelu(as1 + ad1));
        acc0.x = fmaf(w0, xs.x, acc0.x); acc0.y = fmaf(w0, xs.y, acc0.y);
        acc0.z = fmaf(w0, xs.z, acc0.z); acc0.w = fmaf(w0, xs.w, acc0.w);
        acc1.x = fmaf(w1, xs.x, acc1.x); acc1.y = fmaf(w1, xs.y, acc1.y);
        acc1.z = fmaf(w1, xs.z, acc1.z); acc1.w = fmaf(w1, xs.w, acc1.w);
        ws0 += w0; ws1 += w1;
    }
    #pragma unroll
    for (int off = 1; off < 16; off <<= 1) {
        acc0.x += __shfl_xor(acc0.x, off, 64);
        acc0.y += __shfl_xor(acc0.y, off, 64);
        acc0.z += __shfl_xor(acc0.z, off, 64);
        acc0.w += __shfl_xor(acc0.w, off, 64);
        acc1.x += __shfl_xor(acc1.x, off, 64);
        acc1.y += __shfl_xor(acc1.y, off, 64);
        acc1.z += __shfl_xor(acc1.z, off, 64);
        acc1.w += __shfl_xor(acc1.w, off, 64);
        ws0    += __shfl_xor(ws0,    off, 64);
        ws1    += __shfl_xor(ws1,    off, 64);
    }
    if (lane == 0) {
        agg0[n] = acc0;
        agg1[n] = acc1;
        wsA[n]  = make_float2(ws0, ws1);
    }
}

// ---------------------------------------------------------------------------
// k_h2f: out1 built as fp16 in LDS, as2/ad2 reduction, MFMA GEMM -> h2 fp16
// ---------------------------------------------------------------------------
#define H2_NPB 64
#define SROW_H_LD 136
__global__ void __launch_bounds__(256) k_h2f(
    const float4* __restrict__ agg0, const float4* __restrict__ agg1,
    const float2* __restrict__ wsA,
    const float* __restrict__ w1, const float* __restrict__ b1,
    const __half* __restrict__ w2frag,
    const float* __restrict__ B2, const float* __restrict__ E2,
    __half* __restrict__ h2h, float* __restrict__ as2, float* __restrict__ ad2)
{
    __shared__ __align__(16) _Float16 srow[H2_NPB * SROW_H_LD];
    const int tid = threadIdx.x;
    const int bn  = blockIdx.x * H2_NPB;

    #pragma unroll 4
    for (int t = 0; t < 16; ++t) {
        int i = tid + t * 256;
        int r = i >> 6, c2 = i & 63;
        int n = bn + r;
        int head = c2 >> 5;
        float4 a; float ws;
        if (n < N_NODES) {
            a = head ? agg1[n] : agg0[n];
            float2 w = wsA[n];
            ws = head ? w.y : w.x;
        } else { a = make_float4(0.f, 0.f, 0.f, 0.f); ws = 1.f; }
        const float4 wA = ((const float4*)w1)[2 * c2];
        const float4 wB = ((const float4*)w1)[2 * c2 + 1];
        const float2 bb = ((const float2*)b1)[c2];
        float inv = 1.f / ws;
        float v0 = elu_f((a.x * wA.x + a.y * wA.y + a.z * wA.z + a.w * wA.w) * inv + bb.x);
        float v1 = elu_f((a.x * wB.x + a.y * wB.y + a.z * wB.z + a.w * wB.w) * inv + bb.y);
        *(__half2*)&srow[r * SROW_H_LD + 2 * c2] = __floats2half2_rn(v0, v1);
    }
    __syncthreads();

    {
        int r = tid >> 2, q = tid & 3;
        const __half2* row = (const __half2*)&srow[r * SROW_H_LD];
        float ps = 0.f, pd = 0.f;
        #pragma unroll 4
        for (int i = 0; i < 16; ++i) {
            int c2 = q * 16 + i;
            float2 v  = __half22float2(row[c2]);
            float2 Bv = ((const float2*)B2)[c2];
            float2 Ev = ((const float2*)E2)[c2];
            ps += v.x * Bv.x + v.y * Bv.y;
            pd += v.x * Ev.x + v.y * Ev.y;
        }
        ps += __shfl_xor(ps, 1, 64); ps += __shfl_xor(ps, 2, 64);
        pd += __shfl_xor(pd, 1, 64); pd += __shfl_xor(pd, 2, 64);
        int n = bn + r;
        if (q == 0 && n < N_NODES) { as2[n] = ps; ad2[n] = pd; }
    }

    const int lane = tid & 63;
    const int wv   = tid >> 6;
    const int mrow = lane & 15;
    const int kc   = lane >> 4;
    f32x4 acc[4] = {{0.f,0.f,0.f,0.f},{0.f,0.f,0.f,0.f},{0.f,0.f,0.f,0.f},{0.f,0.f,0.f,0.f}};
    const half8* __restrict__ wf = (const half8*)w2frag;
    #pragma unroll
    for (int ks = 0; ks < 4; ++ks) {
        const half8 af = *(const half8*)&srow[(wv * 16 + mrow) * SROW_H_LD + ks * 32 + kc * 8];
        #pragma unroll
        for (int nt = 0; nt < 4; ++nt) {
            const half8 bf = wf[(nt * 4 + ks) * 64 + lane];
            acc[nt] = __builtin_amdgcn_mfma_f32_16x16x32_f16(af, bf, acc[nt], 0, 0, 0);
        }
    }
    #pragma unroll
    for (int nt = 0; nt < 4; ++nt) {
        #pragma unroll
        for (int reg = 0; reg < 4; ++reg) {
            int node = bn + wv * 16 + ((lane >> 4) << 2) + reg;
            int dim  = nt * 16 + (lane & 15);
            if (node < N_NODES) h2h[(size_t)node * 64 + dim] = __float2half(acc[nt][reg]);
        }
    }
}

// ---------------------------------------------------------------------------
// Layer-2 edge weights (coalesced CSR writes); zeroes pad srcs/weights.
// ---------------------------------------------------------------------------
__global__ void __launch_bounds__(256) k_weights2(
    const int* __restrict__ rowptr, const int* __restrict__ deg, int* __restrict__ srcs,
    const float* __restrict__ as2, const float* __restrict__ ad2,
    float* __restrict__ w0p)
{
    int n = blockIdx.x * 16 + (threadIdx.x >> 4);
    int lane = threadIdx.x & 15;
    if (n >= N_NODES) return;
    int beg = rowptr[n], pend = rowptr[n + 1], rend = beg + deg[n];
    float adv = ad2[n];
    for (int j = beg + lane; j < pend; j += 16) {
        if (j < rend) {
            w0p[j] = __expf(lrelu(as2[srcs[j]] + adv));
        } else {
            srcs[j] = 0;     // pad: safe row, zero weight
            w0p[j] = 0.f;
        }
    }
}

// ---------------------------------------------------------------------------
// Gather layer 2, 8-edge-parallel, packed fp16 inner accumulation.
// nbase splits the node range across two launches (profiling visibility;
// semantically identical to the single launch).
// ---------------------------------------------------------------------------
__global__ void __launch_bounds__(256) k_gather2(
    const int* __restrict__ srcs, const int* __restrict__ rowptr,
    const float* __restrict__ wcsr, const _Float16* __restrict__ h2h,
    const float* __restrict__ b2, float* __restrict__ out2, int nbase)
{
    const int tid  = threadIdx.x;
    const int n    = nbase + blockIdx.x * 4 + (tid >> 6);
    const int lane = tid & 63;
    const int eg   = lane >> 3;
    const int dq   = lane & 7;
    const int beg = rowptr[n], end = rowptr[n + 1];

    half8 hacc = {0, 0, 0, 0, 0, 0, 0, 0};
    float wsum = 0.f;
    for (int j = beg + eg; j < end; j += 8) {
        const int   s = srcs[j];
        const float w = wcsr[j];
        const half8 v = *(const half8*)&h2h[(size_t)s * 64 + dq * 8];
        const _Float16 wh = (_Float16)w;
        const half8 ws8 = {wh, wh, wh, wh, wh, wh, wh, wh};
        hacc += v * ws8;                  // 4x v_pk_fma_f16
        wsum += w;
    }
    float a0 = (float)hacc[0], a1 = (float)hacc[1], a2 = (float)hacc[2], a3 = (float)hacc[3];
    float a4 = (float)hacc[4], a5 = (float)hacc[5], a6 = (float)hacc[6], a7 = (float)hacc[7];
    #pragma unroll
    for (int off = 8; off < 64; off <<= 1) {
        a0 += __shfl_xor(a0, off, 64);
        a1 += __shfl_xor(a1, off, 64);
        a2 += __shfl_xor(a2, off, 64);
        a3 += __shfl_xor(a3, off, 64);
        a4 += __shfl_xor(a4, off, 64);
        a5 += __shfl_xor(a5, off, 64);
        a6 += __shfl_xor(a6, off, 64);
        a7 += __shfl_xor(a7, off, 64);
        wsum += __shfl_xor(wsum, off, 64);
    }
    if (eg == 0) {
        const float inv = 1.f / wsum;
        const float4 bA = ((const float4*)b2)[dq * 2];
        const float4 bB = ((const float4*)b2)[dq * 2 + 1];
        float4 oA, oB;
        oA.x = elu_f(a0 * inv + bA.x);
        oA.y = elu_f(a1 * inv + bA.y);
        oA.z = elu_f(a2 * inv + bA.z);
        oA.w = elu_f(a3 * inv + bA.w);
        oB.x = elu_f(a4 * inv + bB.x);
        oB.y = elu_f(a5 * inv + bB.y);
        oB.z = elu_f(a6 * inv + bB.z);
        oB.w = elu_f(a7 * inv + bB.w);
        float4* orow = (float4*)(out2 + (size_t)n * 64);
        orow[dq * 2]     = oA;
        orow[dq * 2 + 1] = oB;
    }
}

// ---------------------------------------------------------------------------
// Global mean pool: batch sorted -> register runs, flush at boundaries
// ---------------------------------------------------------------------------
__global__ void __launch_bounds__(256) k_pool(
    const float* __restrict__ out2, const int* __restrict__ batch,
    float* __restrict__ pool, float* __restrict__ cnt)
{
    const int wv = threadIdx.x >> 6, d = threadIdx.x & 63;
    const int wid = blockIdx.x * 4 + wv;
    const int per = (N_NODES + 2047) / 2048;
    int n0 = wid * per, n1 = min(n0 + per, N_NODES);
    if (n0 >= n1) return;
    float acc = 0.f; int g = batch[n0]; int run = 0;
    for (int n = n0; n < n1; ++n) {
        int gn = batch[n];
        if (gn != g) {
            atomicAdd(&pool[g * 64 + d], acc);
            if (d == 0) atomicAdd(&cnt[g], (float)run);
            acc = 0.f; run = 0; g = gn;
        }
        acc += out2[(size_t)n * 64 + d];
        ++run;
    }
    atomicAdd(&pool[g * 64 + d], acc);
    if (d == 0) atomicAdd(&cnt[g], (float)run);
}

__global__ void k_head(const float* __restrict__ pool, const float* __restrict__ cnt,
                       const float* __restrict__ wp, const float* __restrict__ bp,
                       float* __restrict__ out)
{
    int t = threadIdx.x;
    int g = t >> 4, s = t & 15;
    float c = cnt[g]; if (c < 1.f) c = 1.f;
    float acc = bp[s];
    for (int d = 0; d < 64; ++d) acc += (pool[g * 64 + d] / c) * wp[s * 64 + d];
    out[g * 16 + s] = acc;
}

extern "C" void kernel_launch(void* const* d_in, const int* in_sizes, int n_in,
                              void* d_out, int out_size, void* d_ws, size_t ws_size,
                              hipStream_t stream)
{
    const float* x     = (const float*)d_in[0];
    const int*   ei    = (const int*)  d_in[1];
    const int*   batch = (const int*)  d_in[2];
    const float* w1    = (const float*)d_in[3];
    const float* asr1  = (const float*)d_in[4];
    const float* adr1  = (const float*)d_in[5];
    const float* b1    = (const float*)d_in[6];
    const float* w2    = (const float*)d_in[7];
    const float* asr2  = (const float*)d_in[8];
    const float* adr2  = (const float*)d_in[9];
    const float* b2    = (const float*)d_in[10];
    const float* wp    = (const float*)d_in[11];
    const float* bp    = (const float*)d_in[12];
    float* out = (float*)d_out;

    // Workspace layout (~62 MB)
    float4* agg0 = (float4*)d_ws;                          // N
    float4* agg1 = agg0 + N_NODES;                         // N
    float2* wsA  = (float2*)(agg1 + N_NODES);              // N
    __half* h2h  = (__half*)(wsA + N_NODES);               // N*64 fp16 (16B-aligned)
    float* out2  = (float*)(h2h + (size_t)N_NODES * 64);   // N*64 f32 (16B-aligned)
    float* as2   = out2 + (size_t)N_NODES * 64;            // N
    float* ad2   = as2 + N_NODES;                          // N
    float* pool  = ad2 + N_NODES;                          // 64*64
    float* cnt   = pool + N_GRAPHS * 64;                   // 64
    int* deg     = (int*)(cnt + N_GRAPHS);                 // N+1
    int* rowptr  = deg + N_NODES + 1;                      // N+1
    int* cur     = rowptr + N_NODES + 1;                   // N (scatter cursors)
    int* srcs    = cur + N_NODES;                          // E_CAP
    float* wcsr  = (float*)(srcs + E_CAP);                 // E_CAP (layer-2 weights)
    int* bsum    = (int*)(wcsr + E_CAP);                   // 512 scan scratch
    float* A1    = (float*)(bsum + 512);                   // 8
    float* D1    = A1 + 8;                                 // 8
    float* B2    = D1 + 8;                                 // 128
    float* E2    = B2 + 128;                               // 128
    __half* w2frag = (__half*)(((uintptr_t)(E2 + 128) + 15) & ~(uintptr_t)15); // 8192 fp16, 16B-aligned

    hipMemsetAsync(deg, 0, (size_t)(N_NODES + 1) * sizeof(int), stream);
    hipMemsetAsync(pool, 0, (size_t)(N_GRAPHS * 64 + N_GRAPHS) * sizeof(float), stream);

    // Folded attention projections + fragment-ordered W2 (merged)
    k_preall<<<33, 256, 0, stream>>>(w1, asr1, adr1, w2, asr2, adr2, A1, D1, B2, E2, w2frag);

    // Padded CSR by destination (x8), cursor-based scatter
    const int eb  = (E_TOT + 255) / 256;
    const int nb1 = (N_NODES + 1 + 255) / 256;
    k_count<<<eb, 256, 0, stream>>>(ei, deg);
    k_scan1<<<nb1, 256, 0, stream>>>(deg, rowptr, bsum);
    k_scan2<<<1, 512, 0, stream>>>(bsum, nb1);
    k_scan3<<<nb1, 256, 0, stream>>>(rowptr, cur, bsum);
    k_scatter<<<eb, 256, 0, stream>>>(ei, cur, srcs);

    // Layer-1 aggregation in x-space
    const int gb = (N_NODES + 15) / 16;
    k_gather1x<<<gb, 256, 0, stream>>>(srcs, rowptr, deg, x, A1, D1, agg0, agg1, wsA);

    // Fused out1-build + as2/ad2 + layer-2 GEMM (MFMA)
    k_h2f<<<(N_NODES + H2_NPB - 1) / H2_NPB, 256, 0, stream>>>(
        agg0, agg1, wsA, w1, b1, w2frag, B2, E2, h2h, as2, ad2);

    // Layer-2 weights + aggregate (split into two node-range halves)
    k_weights2<<<gb, 256, 0, stream>>>(rowptr, deg, srcs, as2, ad2, wcsr);
    k_gather2<<<N_NODES / 8, 256, 0, stream>>>(srcs, rowptr, wcsr, (const _Float16*)h2h,
                                               b2, out2, 0);
    k_gather2<<<N_NODES / 8, 256, 0, stream>>>(srcs, rowptr, wcsr, (const _Float16*)h2h,
                                               b2, out2, N_NODES / 2);

    // Mean pool + head
    k_pool<<<512, 256, 0, stream>>>(out2, batch, pool, cnt);
    k_head<<<1, 1024, 0, stream>>>(pool, cnt, wp, bp, out);
}

// Round 13
// 234.215 us; speedup vs baseline: 1.2403x; 1.2403x over previous
//
#include <hip/hip_runtime.h>
#include <hip/hip_fp16.h>

#define N_NODES  100000
#define N_EDGES  1000000
#define E_TOT    1100000   // edges + self-loops
#define E_CAP    1900000   // padded-CSR capacity (deg padded to x8: <= E_TOT + 7*N)
#define N_GRAPHS 64

typedef _Float16 half8 __attribute__((ext_vector_type(8)));
typedef float    f32x4 __attribute__((ext_vector_type(4)));

__device__ __forceinline__ float elu_f(float v) {
    return v > 0.f ? v : expm1f(v);
}

__device__ __forceinline__ float lrelu(float v) {
    return v > 0.f ? v : 0.2f * v;
}

// ---------------------------------------------------------------------------
// k_preall: block 0 = folded attention projections (exact algebra);
//           blocks 1..32 = fragment-ordered fp16 W2 for the MFMA B-operand.
// ---------------------------------------------------------------------------
__global__ void k_preall(const float* __restrict__ w1,
                         const float* __restrict__ as1v, const float* __restrict__ ad1v,
                         const float* __restrict__ w2,
                         const float* __restrict__ as2v, const float* __restrict__ ad2v,
                         float* __restrict__ A1, float* __restrict__ D1,
                         float* __restrict__ B2, float* __restrict__ E2,
                         __half* __restrict__ w2frag)
{
    if (blockIdx.x == 0) {
        int t = threadIdx.x;
        if (t < 128) {
            float acc = 0.f;
            for (int d = 0; d < 64; ++d) acc += w2[d * 128 + t] * as2v[d];
            B2[t] = acc;
        } else {
            int k = t - 128;
            float acc = 0.f;
            for (int d = 0; d < 64; ++d) acc += w2[d * 128 + k] * ad2v[d];
            E2[k] = acc;
        }
        if (t < 8) {
            int h = t >> 2, k = t & 3;
            float acc = 0.f;
            for (int d = 0; d < 64; ++d) acc += w1[(h * 64 + d) * 4 + k] * as1v[h * 64 + d];
            A1[t] = acc;
        } else if (t < 16) {
            int i = t - 8, h = i >> 2, k = i & 3;
            float acc = 0.f;
            for (int d = 0; d < 64; ++d) acc += w1[(h * 64 + d) * 4 + k] * ad1v[h * 64 + d];
            D1[i] = acc;
        }
    } else {
        int f = (blockIdx.x - 1) * 256 + threadIdx.x;  // 8192 total
        int j = f & 7, ln = (f >> 3) & 63, g = f >> 9; // g = nt*4+ks
        int nt = g >> 2, ks = g & 3;
        int col = nt * 16 + (ln & 15);
        int k   = ks * 32 + ((ln >> 4) << 3) + j;
        w2frag[f] = __float2half(w2[col * 128 + k]);
    }
}

// ---------------------------------------------------------------------------
// CSR build (padded to x8): count (with position capture) -> scan -> scatter
// (pos-based, atomic-free scatter — round-11 scheme)
// ---------------------------------------------------------------------------
__global__ void k_count(const int* __restrict__ ei, int* __restrict__ deg, int* __restrict__ pos)
{
    int e = blockIdx.x * blockDim.x + threadIdx.x;
    if (e >= E_TOT) return;
    int dst = (e < N_EDGES) ? ei[N_EDGES + e] : (e - N_EDGES);
    pos[e] = atomicAdd(&deg[dst], 1);
}

__global__ void k_scan1(const int* __restrict__ deg, int* __restrict__ rowptr, int* __restrict__ bsum)
{
    __shared__ int sh[256];
    int tid = threadIdx.x;
    int i = blockIdx.x * 256 + tid;
    int v = (i <= N_NODES) ? ((deg[i] + 7) & ~7) : 0;
    int acc = v;
    sh[tid] = acc; __syncthreads();
    for (int off = 1; off < 256; off <<= 1) {
        int add = (tid >= off) ? sh[tid - off] : 0;
        __syncthreads();
        acc += add;
        sh[tid] = acc;
        __syncthreads();
    }
    if (i <= N_NODES) rowptr[i] = acc - v;
    if (tid == 255) bsum[blockIdx.x] = acc;
}

__global__ void k_scan2(int* __restrict__ bsum, int nb)
{
    __shared__ int sh[512];
    int tid = threadIdx.x;
    int v = (tid < nb) ? bsum[tid] : 0;
    int acc = v;
    sh[tid] = acc; __syncthreads();
    for (int off = 1; off < 512; off <<= 1) {
        int add = (tid >= off) ? sh[tid - off] : 0;
        __syncthreads();
        acc += add;
        sh[tid] = acc;
        __syncthreads();
    }
    if (tid < nb) bsum[tid] = acc - v;
}

__global__ void k_scan3(int* __restrict__ rowptr, const int* __restrict__ bsum)
{
    int i = blockIdx.x * 256 + threadIdx.x;
    if (i <= N_NODES) rowptr[i] += bsum[blockIdx.x];
}

__global__ void k_scatter(const int* __restrict__ ei, const int* __restrict__ rowptr,
                          const int* __restrict__ pos, int* __restrict__ srcs)
{
    int e = blockIdx.x * blockDim.x + threadIdx.x;
    if (e >= E_TOT) return;
    int src = (e < N_EDGES) ? ei[e] : (e - N_EDGES);
    int dst = (e < N_EDGES) ? ei[N_EDGES + e] : (e - N_EDGES);
    srcs[rowptr[dst] + pos[e]] = src;
}

// ---------------------------------------------------------------------------
// Layer-1 aggregation in x-space (16 lanes per node, one edge per lane)
// ---------------------------------------------------------------------------
__global__ void __launch_bounds__(256) k_gather1x(
    const int* __restrict__ srcs, const int* __restrict__ rowptr, const int* __restrict__ deg,
    const float* __restrict__ x,
    const float* __restrict__ A1c, const float* __restrict__ D1c,
    float4* __restrict__ agg0, float4* __restrict__ agg1, float2* __restrict__ wsA)
{
    const int tid  = threadIdx.x;
    const int n    = blockIdx.x * 16 + (tid >> 4);
    const int lane = tid & 15;
    if (n >= N_NODES) return;

    const float4 A0 = ((const float4*)A1c)[0], A1v = ((const float4*)A1c)[1];
    const float4 D0 = ((const float4*)D1c)[0], D1v = ((const float4*)D1c)[1];
    const float4 xn = ((const float4*)x)[n];
    const float ad0 = xn.x * D0.x + xn.y * D0.y + xn.z * D0.z + xn.w * D0.w;
    const float ad1 = xn.x * D1v.x + xn.y * D1v.y + xn.z * D1v.z + xn.w * D1v.w;

    const int beg = rowptr[n], rend = beg + deg[n];
    float4 acc0 = {0.f, 0.f, 0.f, 0.f}, acc1 = {0.f, 0.f, 0.f, 0.f};
    float ws0 = 0.f, ws1 = 0.f;
    for (int j = beg + lane; j < rend; j += 16) {
        const int s = srcs[j];
        const float4 xs = ((const float4*)x)[s];
        const float as0 = xs.x * A0.x + xs.y * A0.y + xs.z * A0.z + xs.w * A0.w;
        const float as1 = xs.x * A1v.x + xs.y * A1v.y + xs.z * A1v.z + xs.w * A1v.w;
        const float w0 = __expf(lrelu(as0 + ad0));
        const float w1 = __expf(lrelu(as1 + ad1));
        acc0.x = fmaf(w0, xs.x, acc0.x); acc0.y = fmaf(w0, xs.y, acc0.y);
        acc0.z = fmaf(w0, xs.z, acc0.z); acc0.w = fmaf(w0, xs.w, acc0.w);
        acc1.x = fmaf(w1, xs.x, acc1.x); acc1.y = fmaf(w1, xs.y, acc1.y);
        acc1.z = fmaf(w1, xs.z, acc1.z); acc1.w = fmaf(w1, xs.w, acc1.w);
        ws0 += w0; ws1 += w1;
    }
    #pragma unroll
    for (int off = 1; off < 16; off <<= 1) {
        acc0.x += __shfl_xor(acc0.x, off, 64);
        acc0.y += __shfl_xor(acc0.y, off, 64);
        acc0.z += __shfl_xor(acc0.z, off, 64);
        acc0.w += __shfl_xor(acc0.w, off, 64);
        acc1.x += __shfl_xor(acc1.x, off, 64);
        acc1.y += __shfl_xor(acc1.y, off, 64);
        acc1.z += __shfl_xor(acc1.z, off, 64);
        acc1.w += __shfl_xor(acc1.w, off, 64);
        ws0    += __shfl_xor(ws0,    off, 64);
        ws1    += __shfl_xor(ws1,    off, 64);
    }
    if (lane == 0) {
        agg0[n] = acc0;
        agg1[n] = acc1;
        wsA[n]  = make_float2(ws0, ws1);
    }
}

// ---------------------------------------------------------------------------
// k_h2f: out1 built as fp16 in LDS, as2/ad2 reduction, MFMA GEMM -> h2 fp16
// ---------------------------------------------------------------------------
#define H2_NPB 64
#define SROW_H_LD 136
__global__ void __launch_bounds__(256) k_h2f(
    const float4* __restrict__ agg0, const float4* __restrict__ agg1,
    const float2* __restrict__ wsA,
    const float* __restrict__ w1, const float* __restrict__ b1,
    const __half* __restrict__ w2frag,
    const float* __restrict__ B2, const float* __restrict__ E2,
    __half* __restrict__ h2h, float* __restrict__ as2, float* __restrict__ ad2)
{
    __shared__ __align__(16) _Float16 srow[H2_NPB * SROW_H_LD];
    const int tid = threadIdx.x;
    const int bn  = blockIdx.x * H2_NPB;

    #pragma unroll 4
    for (int t = 0; t < 16; ++t) {
        int i = tid + t * 256;
        int r = i >> 6, c2 = i & 63;
        int n = bn + r;
        int head = c2 >> 5;
        float4 a; float ws;
        if (n < N_NODES) {
            a = head ? agg1[n] : agg0[n];
            float2 w = wsA[n];
            ws = head ? w.y : w.x;
        } else { a = make_float4(0.f, 0.f, 0.f, 0.f); ws = 1.f; }
        const float4 wA = ((const float4*)w1)[2 * c2];
        const float4 wB = ((const float4*)w1)[2 * c2 + 1];
        const float2 bb = ((const float2*)b1)[c2];
        float inv = 1.f / ws;
        float v0 = elu_f((a.x * wA.x + a.y * wA.y + a.z * wA.z + a.w * wA.w) * inv + bb.x);
        float v1 = elu_f((a.x * wB.x + a.y * wB.y + a.z * wB.z + a.w * wB.w) * inv + bb.y);
        *(__half2*)&srow[r * SROW_H_LD + 2 * c2] = __floats2half2_rn(v0, v1);
    }
    __syncthreads();

    {
        int r = tid >> 2, q = tid & 3;
        const __half2* row = (const __half2*)&srow[r * SROW_H_LD];
        float ps = 0.f, pd = 0.f;
        #pragma unroll 4
        for (int i = 0; i < 16; ++i) {
            int c2 = q * 16 + i;
            float2 v  = __half22float2(row[c2]);
            float2 Bv = ((const float2*)B2)[c2];
            float2 Ev = ((const float2*)E2)[c2];
            ps += v.x * Bv.x + v.y * Bv.y;
            pd += v.x * Ev.x + v.y * Ev.y;
        }
        ps += __shfl_xor(ps, 1, 64); ps += __shfl_xor(ps, 2, 64);
        pd += __shfl_xor(pd, 1, 64); pd += __shfl_xor(pd, 2, 64);
        int n = bn + r;
        if (q == 0 && n < N_NODES) { as2[n] = ps; ad2[n] = pd; }
    }

    const int lane = tid & 63;
    const int wv   = tid >> 6;
    const int mrow = lane & 15;
    const int kc   = lane >> 4;
    f32x4 acc[4] = {{0.f,0.f,0.f,0.f},{0.f,0.f,0.f,0.f},{0.f,0.f,0.f,0.f},{0.f,0.f,0.f,0.f}};
    const half8* __restrict__ wf = (const half8*)w2frag;
    #pragma unroll
    for (int ks = 0; ks < 4; ++ks) {
        const half8 af = *(const half8*)&srow[(wv * 16 + mrow) * SROW_H_LD + ks * 32 + kc * 8];
        #pragma unroll
        for (int nt = 0; nt < 4; ++nt) {
            const half8 bf = wf[(nt * 4 + ks) * 64 + lane];
            acc[nt] = __builtin_amdgcn_mfma_f32_16x16x32_f16(af, bf, acc[nt], 0, 0, 0);
        }
    }
    #pragma unroll
    for (int nt = 0; nt < 4; ++nt) {
        #pragma unroll
        for (int reg = 0; reg < 4; ++reg) {
            int node = bn + wv * 16 + ((lane >> 4) << 2) + reg;
            int dim  = nt * 16 + (lane & 15);
            if (node < N_NODES) h2h[(size_t)node * 64 + dim] = __float2half(acc[nt][reg]);
        }
    }
}

// ---------------------------------------------------------------------------
// Layer-2 edge weights (coalesced CSR writes); zeroes pad srcs/weights.
// ---------------------------------------------------------------------------
__global__ void __launch_bounds__(256) k_weights2(
    const int* __restrict__ rowptr, const int* __restrict__ deg, int* __restrict__ srcs,
    const float* __restrict__ as2, const float* __restrict__ ad2,
    float* __restrict__ w0p)
{
    int n = blockIdx.x * 16 + (threadIdx.x >> 4);
    int lane = threadIdx.x & 15;
    if (n >= N_NODES) return;
    int beg = rowptr[n], pend = rowptr[n + 1], rend = beg + deg[n];
    float adv = ad2[n];
    for (int j = beg + lane; j < pend; j += 16) {
        if (j < rend) {
            w0p[j] = __expf(lrelu(as2[srcs[j]] + adv));
        } else {
            srcs[j] = 0;     // pad: safe row, zero weight
            w0p[j] = 0.f;
        }
    }
}

// ---------------------------------------------------------------------------
// Gather layer 2, 8-edge-parallel, packed fp16 inner accumulation.
// nbase splits the node range across two launches (profiling visibility).
// ---------------------------------------------------------------------------
__global__ void __launch_bounds__(256) k_gather2(
    const int* __restrict__ srcs, const int* __restrict__ rowptr,
    const float* __restrict__ wcsr, const _Float16* __restrict__ h2h,
    const float* __restrict__ b2, float* __restrict__ out2, int nbase)
{
    const int tid  = threadIdx.x;
    const int n    = nbase + blockIdx.x * 4 + (tid >> 6);
    const int lane = tid & 63;
    const int eg   = lane >> 3;
    const int dq   = lane & 7;
    const int beg = rowptr[n], end = rowptr[n + 1];

    half8 hacc = {0, 0, 0, 0, 0, 0, 0, 0};
    float wsum = 0.f;
    for (int j = beg + eg; j < end; j += 8) {
        const int   s = srcs[j];
        const float w = wcsr[j];
        const half8 v = *(const half8*)&h2h[(size_t)s * 64 + dq * 8];
        const _Float16 wh = (_Float16)w;
        const half8 ws8 = {wh, wh, wh, wh, wh, wh, wh, wh};
        hacc += v * ws8;                  // 4x v_pk_fma_f16
        wsum += w;
    }
    float a0 = (float)hacc[0], a1 = (float)hacc[1], a2 = (float)hacc[2], a3 = (float)hacc[3];
    float a4 = (float)hacc[4], a5 = (float)hacc[5], a6 = (float)hacc[6], a7 = (float)hacc[7];
    #pragma unroll
    for (int off = 8; off < 64; off <<= 1) {
        a0 += __shfl_xor(a0, off, 64);
        a1 += __shfl_xor(a1, off, 64);
        a2 += __shfl_xor(a2, off, 64);
        a3 += __shfl_xor(a3, off, 64);
        a4 += __shfl_xor(a4, off, 64);
        a5 += __shfl_xor(a5, off, 64);
        a6 += __shfl_xor(a6, off, 64);
        a7 += __shfl_xor(a7, off, 64);
        wsum += __shfl_xor(wsum, off, 64);
    }
    if (eg == 0) {
        const float inv = 1.f / wsum;
        const float4 bA = ((const float4*)b2)[dq * 2];
        const float4 bB = ((const float4*)b2)[dq * 2 + 1];
        float4 oA, oB;
        oA.x = elu_f(a0 * inv + bA.x);
        oA.y = elu_f(a1 * inv + bA.y);
        oA.z = elu_f(a2 * inv + bA.z);
        oA.w = elu_f(a3 * inv + bA.w);
        oB.x = elu_f(a4 * inv + bB.x);
        oB.y = elu_f(a5 * inv + bB.y);
        oB.z = elu_f(a6 * inv + bB.z);
        oB.w = elu_f(a7 * inv + bB.w);
        float4* orow = (float4*)(out2 + (size_t)n * 64);
        orow[dq * 2]     = oA;
        orow[dq * 2 + 1] = oB;
    }
}

// ---------------------------------------------------------------------------
// Global mean pool: batch sorted -> register runs, flush at boundaries
// ---------------------------------------------------------------------------
__global__ void __launch_bounds__(256) k_pool(
    const float* __restrict__ out2, const int* __restrict__ batch,
    float* __restrict__ pool, float* __restrict__ cnt)
{
    const int wv = threadIdx.x >> 6, d = threadIdx.x & 63;
    const int wid = blockIdx.x * 4 + wv;
    const int per = (N_NODES + 2047) / 2048;
    int n0 = wid * per, n1 = min(n0 + per, N_NODES);
    if (n0 >= n1) return;
    float acc = 0.f; int g = batch[n0]; int run = 0;
    for (int n = n0; n < n1; ++n) {
        int gn = batch[n];
        if (gn != g) {
            atomicAdd(&pool[g * 64 + d], acc);
            if (d == 0) atomicAdd(&cnt[g], (float)run);
            acc = 0.f; run = 0; g = gn;
        }
        acc += out2[(size_t)n * 64 + d];
        ++run;
    }
    atomicAdd(&pool[g * 64 + d], acc);
    if (d == 0) atomicAdd(&cnt[g], (float)run);
}

__global__ void k_head(const float* __restrict__ pool, const float* __restrict__ cnt,
                       const float* __restrict__ wp, const float* __restrict__ bp,
                       float* __restrict__ out)
{
    int t = threadIdx.x;
    int g = t >> 4, s = t & 15;
    float c = cnt[g]; if (c < 1.f) c = 1.f;
    float acc = bp[s];
    for (int d = 0; d < 64; ++d) acc += (pool[g * 64 + d] / c) * wp[s * 64 + d];
    out[g * 16 + s] = acc;
}

extern "C" void kernel_launch(void* const* d_in, const int* in_sizes, int n_in,
                              void* d_out, int out_size, void* d_ws, size_t ws_size,
                              hipStream_t stream)
{
    const float* x     = (const float*)d_in[0];
    const int*   ei    = (const int*)  d_in[1];
    const int*   batch = (const int*)  d_in[2];
    const float* w1    = (const float*)d_in[3];
    const float* asr1  = (const float*)d_in[4];
    const float* adr1  = (const float*)d_in[5];
    const float* b1    = (const float*)d_in[6];
    const float* w2    = (const float*)d_in[7];
    const float* asr2  = (const float*)d_in[8];
    const float* adr2  = (const float*)d_in[9];
    const float* b2    = (const float*)d_in[10];
    const float* wp    = (const float*)d_in[11];
    const float* bp    = (const float*)d_in[12];
    float* out = (float*)d_out;

    // Workspace layout (~66 MB)
    float4* agg0 = (float4*)d_ws;                          // N
    float4* agg1 = agg0 + N_NODES;                         // N
    float2* wsA  = (float2*)(agg1 + N_NODES);              // N
    __half* h2h  = (__half*)(wsA + N_NODES);               // N*64 fp16 (16B-aligned)
    float* out2  = (float*)(h2h + (size_t)N_NODES * 64);   // N*64 f32 (16B-aligned)
    float* as2   = out2 + (size_t)N_NODES * 64;            // N
    float* ad2   = as2 + N_NODES;                          // N
    float* pool  = ad2 + N_NODES;                          // 64*64
    float* cnt   = pool + N_GRAPHS * 64;                   // 64
    int* deg     = (int*)(cnt + N_GRAPHS);                 // N+1
    int* rowptr  = deg + N_NODES + 1;                      // N+1
    int* pos     = rowptr + N_NODES + 1;                   // E_TOT
    int* srcs    = pos + E_TOT;                            // E_CAP
    float* wcsr  = (float*)(srcs + E_CAP);                 // E_CAP (layer-2 weights)
    int* bsum    = (int*)(wcsr + E_CAP);                   // 512 scan scratch
    float* A1    = (float*)(bsum + 512);                   // 8
    float* D1    = A1 + 8;                                 // 8
    float* B2    = D1 + 8;                                 // 128
    float* E2    = B2 + 128;                               // 128
    __half* w2frag = (__half*)(((uintptr_t)(E2 + 128) + 15) & ~(uintptr_t)15); // 8192 fp16, 16B-aligned

    hipMemsetAsync(deg, 0, (size_t)(N_NODES + 1) * sizeof(int), stream);
    hipMemsetAsync(pool, 0, (size_t)(N_GRAPHS * 64 + N_GRAPHS) * sizeof(float), stream);

    // Folded attention projections + fragment-ordered W2 (merged)
    k_preall<<<33, 256, 0, stream>>>(w1, asr1, adr1, w2, asr2, adr2, A1, D1, B2, E2, w2frag);

    // Padded CSR by destination (x8), pos-based scatter (round-11 scheme)
    const int eb  = (E_TOT + 255) / 256;
    const int nb1 = (N_NODES + 1 + 255) / 256;
    k_count<<<eb, 256, 0, stream>>>(ei, deg, pos);
    k_scan1<<<nb1, 256, 0, stream>>>(deg, rowptr, bsum);
    k_scan2<<<1, 512, 0, stream>>>(bsum, nb1);
    k_scan3<<<nb1, 256, 0, stream>>>(rowptr, bsum);
    k_scatter<<<eb, 256, 0, stream>>>(ei, rowptr, pos, srcs);

    // Layer-1 aggregation in x-space
    const int gb = (N_NODES + 15) / 16;
    k_gather1x<<<gb, 256, 0, stream>>>(srcs, rowptr, deg, x, A1, D1, agg0, agg1, wsA);

    // Fused out1-build + as2/ad2 + layer-2 GEMM (MFMA)
    k_h2f<<<(N_NODES + H2_NPB - 1) / H2_NPB, 256, 0, stream>>>(
        agg0, agg1, wsA, w1, b1, w2frag, B2, E2, h2h, as2, ad2);

    // Layer-2 weights + aggregate (split into two node-range halves)
    k_weights2<<<gb, 256, 0, stream>>>(rowptr, deg, srcs, as2, ad2, wcsr);
    k_gather2<<<N_NODES / 8, 256, 0, stream>>>(srcs, rowptr, wcsr, (const _Float16*)h2h,
                                               b2, out2, 0);
    k_gather2<<<N_NODES / 8, 256, 0, stream>>>(srcs, rowptr, wcsr, (const _Float16*)h2h,
                                               b2, out2, N_NODES / 2);

    // Mean pool + head
    k_pool<<<512, 256, 0, stream>>>(out2, batch, pool, cnt);
    k_head<<<1, 1024, 0, stream>>>(pool, cnt, wp, bp, out);
}

// Round 14
// 215.039 us; speedup vs baseline: 1.3509x; 1.0892x over previous
//
#include <hip/hip_runtime.h>
#include <hip/hip_fp16.h>

#define N_NODES  100000
#define N_EDGES  1000000
#define E_TOT    1100000   // edges + self-loops
#define E_CAP    1900000   // padded-CSR capacity (deg padded to x8: <= E_TOT + 7*N)
#define N_GRAPHS 64

// counting-sort CSR parameters
#define BSH    9
#define BSIZE  512                                   // nodes per bucket
#define NBUCK  ((N_NODES + BSIZE - 1) / BSIZE)       // 196
#define CHUNK  4096
#define NBLKS  ((E_TOT + CHUNK - 1) / CHUNK)         // 269

typedef _Float16 half8 __attribute__((ext_vector_type(8)));
typedef float    f32x4 __attribute__((ext_vector_type(4)));

__device__ __forceinline__ float elu_f(float v) {
    return v > 0.f ? v : expm1f(v);
}

__device__ __forceinline__ float lrelu(float v) {
    return v > 0.f ? v : 0.2f * v;
}

// ---------------------------------------------------------------------------
// k_preall: block 0 = folded attention projections (exact algebra);
//           blocks 1..32 = fragment-ordered fp16 W2 for the MFMA B-operand.
// ---------------------------------------------------------------------------
__global__ void k_preall(const float* __restrict__ w1,
                         const float* __restrict__ as1v, const float* __restrict__ ad1v,
                         const float* __restrict__ w2,
                         const float* __restrict__ as2v, const float* __restrict__ ad2v,
                         float* __restrict__ A1, float* __restrict__ D1,
                         float* __restrict__ B2, float* __restrict__ E2,
                         __half* __restrict__ w2frag)
{
    if (blockIdx.x == 0) {
        int t = threadIdx.x;
        if (t < 128) {
            float acc = 0.f;
            for (int d = 0; d < 64; ++d) acc += w2[d * 128 + t] * as2v[d];
            B2[t] = acc;
        } else {
            int k = t - 128;
            float acc = 0.f;
            for (int d = 0; d < 64; ++d) acc += w2[d * 128 + k] * ad2v[d];
            E2[k] = acc;
        }
        if (t < 8) {
            int h = t >> 2, k = t & 3;
            float acc = 0.f;
            for (int d = 0; d < 64; ++d) acc += w1[(h * 64 + d) * 4 + k] * as1v[h * 64 + d];
            A1[t] = acc;
        } else if (t < 16) {
            int i = t - 8, h = i >> 2, k = i & 3;
            float acc = 0.f;
            for (int d = 0; d < 64; ++d) acc += w1[(h * 64 + d) * 4 + k] * ad1v[h * 64 + d];
            D1[i] = acc;
        }
    } else {
        int f = (blockIdx.x - 1) * 256 + threadIdx.x;  // 8192 total
        int j = f & 7, ln = (f >> 3) & 63, g = f >> 9; // g = nt*4+ks
        int nt = g >> 2, ks = g & 3;
        int col = nt * 16 + (ln & 15);
        int k   = ks * 32 + ((ln >> 4) << 3) + j;
        w2frag[f] = __float2half(w2[col * 128 + k]);
    }
}

// ---------------------------------------------------------------------------
// Counting-sort CSR build — no per-edge global atomics.
// P1: per-block LDS bucket histogram; reserve per-(block,bucket) offsets
//     via 196 global atomics per block (53K total).
// ---------------------------------------------------------------------------
__global__ void __launch_bounds__(256) k_bin1(
    const int* __restrict__ ei, int* __restrict__ bucketCount, int* __restrict__ blockoff)
{
    __shared__ int hist[NBUCK];
    const int t = threadIdx.x;
    for (int i = t; i < NBUCK; i += 256) hist[i] = 0;
    __syncthreads();
    const int e0 = blockIdx.x * CHUNK;
    for (int i = t; i < CHUNK; i += 256) {
        int e = e0 + i;
        if (e < E_TOT) {
            int dst = (e < N_EDGES) ? ei[N_EDGES + e] : (e - N_EDGES);
            atomicAdd(&hist[dst >> BSH], 1);
        }
    }
    __syncthreads();
    for (int i = t; i < NBUCK; i += 256)
        blockoff[blockIdx.x * NBUCK + i] = atomicAdd(&bucketCount[i], hist[i]);
}

// P2: exclusive scan of bucketCount[196] -> bucketStart
__global__ void k_bscan(const int* __restrict__ bucketCount, int* __restrict__ bucketStart)
{
    __shared__ int sh[256];
    int t = threadIdx.x;
    int v = (t < NBUCK) ? bucketCount[t] : 0;
    int acc = v;
    sh[t] = acc; __syncthreads();
    for (int off = 1; off < 256; off <<= 1) {
        int add = (t >= off) ? sh[t - off] : 0;
        __syncthreads();
        acc += add; sh[t] = acc; __syncthreads();
    }
    if (t < NBUCK) bucketStart[t] = acc - v;
}

// P3: scatter packed (src | dstlocal<<17) into bucket regions via LDS cursors
__global__ void __launch_bounds__(256) k_bin2(
    const int* __restrict__ ei, const int* __restrict__ bucketStart,
    const int* __restrict__ blockoff, unsigned int* __restrict__ bucketed)
{
    __shared__ int cur[NBUCK];
    const int t = threadIdx.x;
    for (int i = t; i < NBUCK; i += 256)
        cur[i] = bucketStart[i] + blockoff[blockIdx.x * NBUCK + i];
    __syncthreads();
    const int e0 = blockIdx.x * CHUNK;
    for (int i = t; i < CHUNK; i += 256) {
        int e = e0 + i;
        if (e < E_TOT) {
            int src = (e < N_EDGES) ? ei[e] : (e - N_EDGES);
            int dst = (e < N_EDGES) ? ei[N_EDGES + e] : (e - N_EDGES);
            int b = dst >> BSH;
            int p = atomicAdd(&cur[b], 1);
            bucketed[p] = (unsigned)src | ((unsigned)(dst & (BSIZE - 1)) << 17);
        }
    }
}

// P4a: per-bucket LDS histogram -> deg; padded exclusive scan -> local rowptr;
//      padded bucket total -> bucketPad
__global__ void __launch_bounds__(256) k_bhist(
    const unsigned int* __restrict__ bucketed,
    const int* __restrict__ bucketStart, const int* __restrict__ bucketCount,
    int* __restrict__ deg, int* __restrict__ rowptr, int* __restrict__ bucketPad)
{
    __shared__ int hist[BSIZE];
    __shared__ int sh[256];
    const int t = threadIdx.x;
    const int b = blockIdx.x;
    hist[t] = 0; hist[t + 256] = 0;
    __syncthreads();
    const int beg = bucketStart[b], cnt = bucketCount[b];
    for (int i = t; i < cnt; i += 256)
        atomicAdd(&hist[bucketed[beg + i] >> 17], 1);
    __syncthreads();
    int h0 = hist[2 * t], h1 = hist[2 * t + 1];
    int a = (h0 + 7) & ~7, c = (h1 + 7) & ~7;
    int s = a + c;
    sh[t] = s; __syncthreads();
    for (int off = 1; off < 256; off <<= 1) {
        int add = (t >= off) ? sh[t - off] : 0;
        __syncthreads();
        s += add; sh[t] = s; __syncthreads();
    }
    int base = s - a - c;                 // exclusive padded prefix before node 2t
    const int n0 = b * BSIZE;
    int na = n0 + 2 * t, nb = n0 + 2 * t + 1;
    if (na < N_NODES) { deg[na] = h0; rowptr[na] = base; }
    if (nb < N_NODES) { deg[nb] = h1; rowptr[nb] = base + a; }
    if (t == 255) bucketPad[b] = s;       // padded bucket total
}

// P4b: exclusive scan of bucketPad -> bucketBase; rowptr[N] = grand total
__global__ void k_bscan2(const int* __restrict__ bucketPad, int* __restrict__ bucketBase,
                         int* __restrict__ rowptr)
{
    __shared__ int sh[256];
    int t = threadIdx.x;
    int v = (t < NBUCK) ? bucketPad[t] : 0;
    int acc = v;
    sh[t] = acc; __syncthreads();
    for (int off = 1; off < 256; off <<= 1) {
        int add = (t >= off) ? sh[t - off] : 0;
        __syncthreads();
        acc += add; sh[t] = acc; __syncthreads();
    }
    if (t < NBUCK) bucketBase[t] = acc - v;
    if (t == NBUCK - 1) rowptr[N_NODES] = acc;
}

// P4c: finalize rowptr (+base) and scatter srcs via LDS cursor atomics
__global__ void __launch_bounds__(256) k_bscat(
    const unsigned int* __restrict__ bucketed,
    const int* __restrict__ bucketStart, const int* __restrict__ bucketCount,
    const int* __restrict__ bucketBase, int* __restrict__ rowptr, int* __restrict__ srcs)
{
    __shared__ int cur[BSIZE];
    const int t = threadIdx.x;
    const int b = blockIdx.x;
    const int base = bucketBase[b];
    const int n0 = b * BSIZE;
    #pragma unroll
    for (int k = 0; k < 2; ++k) {
        int nl = t + k * 256;
        int n = n0 + nl;
        if (n < N_NODES) {
            int r = rowptr[n] + base;
            rowptr[n] = r;
            cur[nl] = r;
        }
    }
    __syncthreads();
    const int beg = bucketStart[b], cnt = bucketCount[b];
    for (int i = t; i < cnt; i += 256) {
        unsigned p = bucketed[beg + i];
        int rank = atomicAdd(&cur[p >> 17], 1);
        srcs[rank] = (int)(p & 0x1FFFFu);
    }
}

// ---------------------------------------------------------------------------
// Layer-1 aggregation in x-space (16 lanes per node, one edge per lane)
// ---------------------------------------------------------------------------
__global__ void __launch_bounds__(256) k_gather1x(
    const int* __restrict__ srcs, const int* __restrict__ rowptr, const int* __restrict__ deg,
    const float* __restrict__ x,
    const float* __restrict__ A1c, const float* __restrict__ D1c,
    float4* __restrict__ agg0, float4* __restrict__ agg1, float2* __restrict__ wsA)
{
    const int tid  = threadIdx.x;
    const int n    = blockIdx.x * 16 + (tid >> 4);
    const int lane = tid & 15;
    if (n >= N_NODES) return;

    const float4 A0 = ((const float4*)A1c)[0], A1v = ((const float4*)A1c)[1];
    const float4 D0 = ((const float4*)D1c)[0], D1v = ((const float4*)D1c)[1];
    const float4 xn = ((const float4*)x)[n];
    const float ad0 = xn.x * D0.x + xn.y * D0.y + xn.z * D0.z + xn.w * D0.w;
    const float ad1 = xn.x * D1v.x + xn.y * D1v.y + xn.z * D1v.z + xn.w * D1v.w;

    const int beg = rowptr[n], rend = beg + deg[n];
    float4 acc0 = {0.f, 0.f, 0.f, 0.f}, acc1 = {0.f, 0.f, 0.f, 0.f};
    float ws0 = 0.f, ws1 = 0.f;
    for (int j = beg + lane; j < rend; j += 16) {
        const int s = srcs[j];
        const float4 xs = ((const float4*)x)[s];
        const float as0 = xs.x * A0.x + xs.y * A0.y + xs.z * A0.z + xs.w * A0.w;
        const float as1 = xs.x * A1v.x + xs.y * A1v.y + xs.z * A1v.z + xs.w * A1v.w;
        const float w0 = __expf(lrelu(as0 + ad0));
        const float w1 = __expf(lrelu(as1 + ad1));
        acc0.x = fmaf(w0, xs.x, acc0.x); acc0.y = fmaf(w0, xs.y, acc0.y);
        acc0.z = fmaf(w0, xs.z, acc0.z); acc0.w = fmaf(w0, xs.w, acc0.w);
        acc1.x = fmaf(w1, xs.x, acc1.x); acc1.y = fmaf(w1, xs.y, acc1.y);
        acc1.z = fmaf(w1, xs.z, acc1.z); acc1.w = fmaf(w1, xs.w, acc1.w);
        ws0 += w0; ws1 += w1;
    }
    #pragma unroll
    for (int off = 1; off < 16; off <<= 1) {
        acc0.x += __shfl_xor(acc0.x, off, 64);
        acc0.y += __shfl_xor(acc0.y, off, 64);
        acc0.z += __shfl_xor(acc0.z, off, 64);
        acc0.w += __shfl_xor(acc0.w, off, 64);
        acc1.x += __shfl_xor(acc1.x, off, 64);
        acc1.y += __shfl_xor(acc1.y, off, 64);
        acc1.z += __shfl_xor(acc1.z, off, 64);
        acc1.w += __shfl_xor(acc1.w, off, 64);
        ws0    += __shfl_xor(ws0,    off, 64);
        ws1    += __shfl_xor(ws1,    off, 64);
    }
    if (lane == 0) {
        agg0[n] = acc0;
        agg1[n] = acc1;
        wsA[n]  = make_float2(ws0, ws1);
    }
}

// ---------------------------------------------------------------------------
// k_h2f: out1 built as fp16 in LDS, as2/ad2 reduction, MFMA GEMM -> h2 fp16
// ---------------------------------------------------------------------------
#define H2_NPB 64
#define SROW_H_LD 136
__global__ void __launch_bounds__(256) k_h2f(
    const float4* __restrict__ agg0, const float4* __restrict__ agg1,
    const float2* __restrict__ wsA,
    const float* __restrict__ w1, const float* __restrict__ b1,
    const __half* __restrict__ w2frag,
    const float* __restrict__ B2, const float* __restrict__ E2,
    __half* __restrict__ h2h, float* __restrict__ as2, float* __restrict__ ad2)
{
    __shared__ __align__(16) _Float16 srow[H2_NPB * SROW_H_LD];
    const int tid = threadIdx.x;
    const int bn  = blockIdx.x * H2_NPB;

    #pragma unroll 4
    for (int t = 0; t < 16; ++t) {
        int i = tid + t * 256;
        int r = i >> 6, c2 = i & 63;
        int n = bn + r;
        int head = c2 >> 5;
        float4 a; float ws;
        if (n < N_NODES) {
            a = head ? agg1[n] : agg0[n];
            float2 w = wsA[n];
            ws = head ? w.y : w.x;
        } else { a = make_float4(0.f, 0.f, 0.f, 0.f); ws = 1.f; }
        const float4 wA = ((const float4*)w1)[2 * c2];
        const float4 wB = ((const float4*)w1)[2 * c2 + 1];
        const float2 bb = ((const float2*)b1)[c2];
        float inv = 1.f / ws;
        float v0 = elu_f((a.x * wA.x + a.y * wA.y + a.z * wA.z + a.w * wA.w) * inv + bb.x);
        float v1 = elu_f((a.x * wB.x + a.y * wB.y + a.z * wB.z + a.w * wB.w) * inv + bb.y);
        *(__half2*)&srow[r * SROW_H_LD + 2 * c2] = __floats2half2_rn(v0, v1);
    }
    __syncthreads();

    {
        int r = tid >> 2, q = tid & 3;
        const __half2* row = (const __half2*)&srow[r * SROW_H_LD];
        float ps = 0.f, pd = 0.f;
        #pragma unroll 4
        for (int i = 0; i < 16; ++i) {
            int c2 = q * 16 + i;
            float2 v  = __half22float2(row[c2]);
            float2 Bv = ((const float2*)B2)[c2];
            float2 Ev = ((const float2*)E2)[c2];
            ps += v.x * Bv.x + v.y * Bv.y;
            pd += v.x * Ev.x + v.y * Ev.y;
        }
        ps += __shfl_xor(ps, 1, 64); ps += __shfl_xor(ps, 2, 64);
        pd += __shfl_xor(pd, 1, 64); pd += __shfl_xor(pd, 2, 64);
        int n = bn + r;
        if (q == 0 && n < N_NODES) { as2[n] = ps; ad2[n] = pd; }
    }

    const int lane = tid & 63;
    const int wv   = tid >> 6;
    const int mrow = lane & 15;
    const int kc   = lane >> 4;
    f32x4 acc[4] = {{0.f,0.f,0.f,0.f},{0.f,0.f,0.f,0.f},{0.f,0.f,0.f,0.f},{0.f,0.f,0.f,0.f}};
    const half8* __restrict__ wf = (const half8*)w2frag;
    #pragma unroll
    for (int ks = 0; ks < 4; ++ks) {
        const half8 af = *(const half8*)&srow[(wv * 16 + mrow) * SROW_H_LD + ks * 32 + kc * 8];
        #pragma unroll
        for (int nt = 0; nt < 4; ++nt) {
            const half8 bf = wf[(nt * 4 + ks) * 64 + lane];
            acc[nt] = __builtin_amdgcn_mfma_f32_16x16x32_f16(af, bf, acc[nt], 0, 0, 0);
        }
    }
    #pragma unroll
    for (int nt = 0; nt < 4; ++nt) {
        #pragma unroll
        for (int reg = 0; reg < 4; ++reg) {
            int node = bn + wv * 16 + ((lane >> 4) << 2) + reg;
            int dim  = nt * 16 + (lane & 15);
            if (node < N_NODES) h2h[(size_t)node * 64 + dim] = __float2half(acc[nt][reg]);
        }
    }
}

// ---------------------------------------------------------------------------
// Layer-2 edge weights (coalesced CSR writes); zeroes pad srcs/weights.
// ---------------------------------------------------------------------------
__global__ void __launch_bounds__(256) k_weights2(
    const int* __restrict__ rowptr, const int* __restrict__ deg, int* __restrict__ srcs,
    const float* __restrict__ as2, const float* __restrict__ ad2,
    float* __restrict__ w0p)
{
    int n = blockIdx.x * 16 + (threadIdx.x >> 4);
    int lane = threadIdx.x & 15;
    if (n >= N_NODES) return;
    int beg = rowptr[n], pend = rowptr[n + 1], rend = beg + deg[n];
    float adv = ad2[n];
    for (int j = beg + lane; j < pend; j += 16) {
        if (j < rend) {
            w0p[j] = __expf(lrelu(as2[srcs[j]] + adv));
        } else {
            srcs[j] = 0;     // pad: safe row, zero weight
            w0p[j] = 0.f;
        }
    }
}

// ---------------------------------------------------------------------------
// Gather layer 2, 8-edge-parallel, packed fp16 inner accumulation.
// nbase splits the node range across two launches (profiling visibility).
// ---------------------------------------------------------------------------
__global__ void __launch_bounds__(256) k_gather2(
    const int* __restrict__ srcs, const int* __restrict__ rowptr,
    const float* __restrict__ wcsr, const _Float16* __restrict__ h2h,
    const float* __restrict__ b2, float* __restrict__ out2, int nbase)
{
    const int tid  = threadIdx.x;
    const int n    = nbase + blockIdx.x * 4 + (tid >> 6);
    const int lane = tid & 63;
    const int eg   = lane >> 3;
    const int dq   = lane & 7;
    const int beg = rowptr[n], end = rowptr[n + 1];

    half8 hacc = {0, 0, 0, 0, 0, 0, 0, 0};
    float wsum = 0.f;
    for (int j = beg + eg; j < end; j += 8) {
        const int   s = srcs[j];
        const float w = wcsr[j];
        const half8 v = *(const half8*)&h2h[(size_t)s * 64 + dq * 8];
        const _Float16 wh = (_Float16)w;
        const half8 ws8 = {wh, wh, wh, wh, wh, wh, wh, wh};
        hacc += v * ws8;                  // 4x v_pk_fma_f16
        wsum += w;
    }
    float a0 = (float)hacc[0], a1 = (float)hacc[1], a2 = (float)hacc[2], a3 = (float)hacc[3];
    float a4 = (float)hacc[4], a5 = (float)hacc[5], a6 = (float)hacc[6], a7 = (float)hacc[7];
    #pragma unroll
    for (int off = 8; off < 64; off <<= 1) {
        a0 += __shfl_xor(a0, off, 64);
        a1 += __shfl_xor(a1, off, 64);
        a2 += __shfl_xor(a2, off, 64);
        a3 += __shfl_xor(a3, off, 64);
        a4 += __shfl_xor(a4, off, 64);
        a5 += __shfl_xor(a5, off, 64);
        a6 += __shfl_xor(a6, off, 64);
        a7 += __shfl_xor(a7, off, 64);
        wsum += __shfl_xor(wsum, off, 64);
    }
    if (eg == 0) {
        const float inv = 1.f / wsum;
        const float4 bA = ((const float4*)b2)[dq * 2];
        const float4 bB = ((const float4*)b2)[dq * 2 + 1];
        float4 oA, oB;
        oA.x = elu_f(a0 * inv + bA.x);
        oA.y = elu_f(a1 * inv + bA.y);
        oA.z = elu_f(a2 * inv + bA.z);
        oA.w = elu_f(a3 * inv + bA.w);
        oB.x = elu_f(a4 * inv + bB.x);
        oB.y = elu_f(a5 * inv + bB.y);
        oB.z = elu_f(a6 * inv + bB.z);
        oB.w = elu_f(a7 * inv + bB.w);
        float4* orow = (float4*)(out2 + (size_t)n * 64);
        orow[dq * 2]     = oA;
        orow[dq * 2 + 1] = oB;
    }
}

// ---------------------------------------------------------------------------
// Global mean pool: batch sorted -> register runs, flush at boundaries
// ---------------------------------------------------------------------------
__global__ void __launch_bounds__(256) k_pool(
    const float* __restrict__ out2, const int* __restrict__ batch,
    float* __restrict__ pool, float* __restrict__ cnt)
{
    const int wv = threadIdx.x >> 6, d = threadIdx.x & 63;
    const int wid = blockIdx.x * 4 + wv;
    const int per = (N_NODES + 2047) / 2048;
    int n0 = wid * per, n1 = min(n0 + per, N_NODES);
    if (n0 >= n1) return;
    float acc = 0.f; int g = batch[n0]; int run = 0;
    for (int n = n0; n < n1; ++n) {
        int gn = batch[n];
        if (gn != g) {
            atomicAdd(&pool[g * 64 + d], acc);
            if (d == 0) atomicAdd(&cnt[g], (float)run);
            acc = 0.f; run = 0; g = gn;
        }
        acc += out2[(size_t)n * 64 + d];
        ++run;
    }
    atomicAdd(&pool[g * 64 + d], acc);
    if (d == 0) atomicAdd(&cnt[g], (float)run);
}

__global__ void k_head(const float* __restrict__ pool, const float* __restrict__ cnt,
                       const float* __restrict__ wp, const float* __restrict__ bp,
                       float* __restrict__ out)
{
    int t = threadIdx.x;
    int g = t >> 4, s = t & 15;
    float c = cnt[g]; if (c < 1.f) c = 1.f;
    float acc = bp[s];
    for (int d = 0; d < 64; ++d) acc += (pool[g * 64 + d] / c) * wp[s * 64 + d];
    out[g * 16 + s] = acc;
}

extern "C" void kernel_launch(void* const* d_in, const int* in_sizes, int n_in,
                              void* d_out, int out_size, void* d_ws, size_t ws_size,
                              hipStream_t stream)
{
    const float* x     = (const float*)d_in[0];
    const int*   ei    = (const int*)  d_in[1];
    const int*   batch = (const int*)  d_in[2];
    const float* w1    = (const float*)d_in[3];
    const float* asr1  = (const float*)d_in[4];
    const float* adr1  = (const float*)d_in[5];
    const float* b1    = (const float*)d_in[6];
    const float* w2    = (const float*)d_in[7];
    const float* asr2  = (const float*)d_in[8];
    const float* adr2  = (const float*)d_in[9];
    const float* b2    = (const float*)d_in[10];
    const float* wp    = (const float*)d_in[11];
    const float* bp    = (const float*)d_in[12];
    float* out = (float*)d_out;

    // Workspace layout (~66 MB)
    float4* agg0 = (float4*)d_ws;                          // N
    float4* agg1 = agg0 + N_NODES;                         // N
    float2* wsA  = (float2*)(agg1 + N_NODES);              // N
    __half* h2h  = (__half*)(wsA + N_NODES);               // N*64 fp16 (16B-aligned)
    float* out2  = (float*)(h2h + (size_t)N_NODES * 64);   // N*64 f32 (16B-aligned)
    float* as2   = out2 + (size_t)N_NODES * 64;            // N
    float* ad2   = as2 + N_NODES;                          // N
    float* pool  = ad2 + N_NODES;                          // 64*64
    float* cnt   = pool + N_GRAPHS * 64;                   // 64
    int* deg     = (int*)(cnt + N_GRAPHS);                 // N
    int* rowptr  = deg + N_NODES;                          // N+1
    unsigned int* bucketed = (unsigned int*)(rowptr + N_NODES + 1); // E_TOT
    int* srcs    = (int*)(bucketed + E_TOT);               // E_CAP
    float* wcsr  = (float*)(srcs + E_CAP);                 // E_CAP (layer-2 weights)
    int* blockoff    = (int*)(wcsr + E_CAP);               // NBLKS*NBUCK
    int* bucketCount = blockoff + NBLKS * NBUCK;           // NBUCK
    int* bucketStart = bucketCount + NBUCK;                // NBUCK
    int* bucketPad   = bucketStart + NBUCK;                // NBUCK
    int* bucketBase  = bucketPad + NBUCK;                  // NBUCK
    float* A1    = (float*)(bucketBase + NBUCK);           // 8
    float* D1    = A1 + 8;                                 // 8
    float* B2    = D1 + 8;                                 // 128
    float* E2    = B2 + 128;                               // 128
    __half* w2frag = (__half*)(((uintptr_t)(E2 + 128) + 15) & ~(uintptr_t)15); // 8192 fp16

    hipMemsetAsync(bucketCount, 0, NBUCK * sizeof(int), stream);
    hipMemsetAsync(pool, 0, (size_t)(N_GRAPHS * 64 + N_GRAPHS) * sizeof(float), stream);

    // Folded attention projections + fragment-ordered W2 (merged)
    k_preall<<<33, 256, 0, stream>>>(w1, asr1, adr1, w2, asr2, adr2, A1, D1, B2, E2, w2frag);

    // Counting-sort CSR build (padded x8, no per-edge global atomics)
    k_bin1 <<<NBLKS, 256, 0, stream>>>(ei, bucketCount, blockoff);
    k_bscan<<<1, 256, 0, stream>>>(bucketCount, bucketStart);
    k_bin2 <<<NBLKS, 256, 0, stream>>>(ei, bucketStart, blockoff, bucketed);
    k_bhist<<<NBUCK, 256, 0, stream>>>(bucketed, bucketStart, bucketCount, deg, rowptr, bucketPad);
    k_bscan2<<<1, 256, 0, stream>>>(bucketPad, bucketBase, rowptr);
    k_bscat<<<NBUCK, 256, 0, stream>>>(bucketed, bucketStart, bucketCount, bucketBase, rowptr, srcs);

    // Layer-1 aggregation in x-space
    const int gb = (N_NODES + 15) / 16;
    k_gather1x<<<gb, 256, 0, stream>>>(srcs, rowptr, deg, x, A1, D1, agg0, agg1, wsA);

    // Fused out1-build + as2/ad2 + layer-2 GEMM (MFMA)
    k_h2f<<<(N_NODES + H2_NPB - 1) / H2_NPB, 256, 0, stream>>>(
        agg0, agg1, wsA, w1, b1, w2frag, B2, E2, h2h, as2, ad2);

    // Layer-2 weights + aggregate (split into two node-range halves)
    k_weights2<<<gb, 256, 0, stream>>>(rowptr, deg, srcs, as2, ad2, wcsr);
    k_gather2<<<N_NODES / 8, 256, 0, stream>>>(srcs, rowptr, wcsr, (const _Float16*)h2h,
                                               b2, out2, 0);
    k_gather2<<<N_NODES / 8, 256, 0, stream>>>(srcs, rowptr, wcsr, (const _Float16*)h2h,
                                               b2, out2, N_NODES / 2);

    // Mean pool + head
    k_pool<<<512, 256, 0, stream>>>(out2, batch, pool, cnt);
    k_head<<<1, 1024, 0, stream>>>(pool, cnt, wp, bp, out);
}

// Round 15
// 197.509 us; speedup vs baseline: 1.4708x; 1.0888x over previous
//
#include <hip/hip_runtime.h>
#include <hip/hip_fp16.h>

#define N_NODES  100000
#define N_EDGES  1000000
#define E_TOT    1100000   // edges + self-loops
#define E_CAP    1900000   // padded-CSR capacity (deg padded to x8: <= E_TOT + 7*N)
#define N_GRAPHS 64

// counting-sort CSR parameters
#define BSH    9
#define BSIZE  512                                   // nodes per bucket
#define NBUCK  ((N_NODES + BSIZE - 1) / BSIZE)       // 196
#define CHUNK  4096
#define NBLKS  ((E_TOT + CHUNK - 1) / CHUNK)         // 269

typedef _Float16 half8 __attribute__((ext_vector_type(8)));
typedef float    f32x4 __attribute__((ext_vector_type(4)));

__device__ __forceinline__ float elu_f(float v) {
    return v > 0.f ? v : expm1f(v);
}

__device__ __forceinline__ float lrelu(float v) {
    return v > 0.f ? v : 0.2f * v;
}

// ---------------------------------------------------------------------------
// k_preall: block 0 = folded attention projections + zero bucketCount;
//           blocks 1..32 = fragment-ordered fp16 W2 (+ zero pool/cnt).
// ---------------------------------------------------------------------------
__global__ void k_preall(const float* __restrict__ w1,
                         const float* __restrict__ as1v, const float* __restrict__ ad1v,
                         const float* __restrict__ w2,
                         const float* __restrict__ as2v, const float* __restrict__ ad2v,
                         float* __restrict__ A1, float* __restrict__ D1,
                         float* __restrict__ B2, float* __restrict__ E2,
                         __half* __restrict__ w2frag,
                         int* __restrict__ bucketCount, float* __restrict__ poolcnt)
{
    if (blockIdx.x == 0) {
        int t = threadIdx.x;
        if (t < 128) {
            float acc = 0.f;
            for (int d = 0; d < 64; ++d) acc += w2[d * 128 + t] * as2v[d];
            B2[t] = acc;
        } else {
            int k = t - 128;
            float acc = 0.f;
            for (int d = 0; d < 64; ++d) acc += w2[d * 128 + k] * ad2v[d];
            E2[k] = acc;
        }
        if (t < 8) {
            int h = t >> 2, k = t & 3;
            float acc = 0.f;
            for (int d = 0; d < 64; ++d) acc += w1[(h * 64 + d) * 4 + k] * as1v[h * 64 + d];
            A1[t] = acc;
        } else if (t < 16) {
            int i = t - 8, h = i >> 2, k = i & 3;
            float acc = 0.f;
            for (int d = 0; d < 64; ++d) acc += w1[(h * 64 + d) * 4 + k] * ad1v[h * 64 + d];
            D1[i] = acc;
        }
        if (t < NBUCK) bucketCount[t] = 0;
    } else {
        int f = (blockIdx.x - 1) * 256 + threadIdx.x;  // 8192 total
        int j = f & 7, ln = (f >> 3) & 63, g = f >> 9; // g = nt*4+ks
        int nt = g >> 2, ks = g & 3;
        int col = nt * 16 + (ln & 15);
        int k   = ks * 32 + ((ln >> 4) << 3) + j;
        w2frag[f] = __float2half(w2[col * 128 + k]);
        int z = (blockIdx.x - 1) * 256 + threadIdx.x;
        if (z < N_GRAPHS * 64 + N_GRAPHS) poolcnt[z] = 0.f;
    }
}

// ---------------------------------------------------------------------------
// Counting-sort CSR build — no per-edge global atomics.
// ---------------------------------------------------------------------------
__global__ void __launch_bounds__(256) k_bin1(
    const int* __restrict__ ei, int* __restrict__ bucketCount, int* __restrict__ blockoff)
{
    __shared__ int hist[NBUCK];
    const int t = threadIdx.x;
    for (int i = t; i < NBUCK; i += 256) hist[i] = 0;
    __syncthreads();
    const int e0 = blockIdx.x * CHUNK;
    for (int i = t; i < CHUNK; i += 256) {
        int e = e0 + i;
        if (e < E_TOT) {
            int dst = (e < N_EDGES) ? ei[N_EDGES + e] : (e - N_EDGES);
            atomicAdd(&hist[dst >> BSH], 1);
        }
    }
    __syncthreads();
    for (int i = t; i < NBUCK; i += 256)
        blockoff[blockIdx.x * NBUCK + i] = atomicAdd(&bucketCount[i], hist[i]);
}

__global__ void k_bscan(const int* __restrict__ bucketCount, int* __restrict__ bucketStart)
{
    __shared__ int sh[256];
    int t = threadIdx.x;
    int v = (t < NBUCK) ? bucketCount[t] : 0;
    int acc = v;
    sh[t] = acc; __syncthreads();
    for (int off = 1; off < 256; off <<= 1) {
        int add = (t >= off) ? sh[t - off] : 0;
        __syncthreads();
        acc += add; sh[t] = acc; __syncthreads();
    }
    if (t < NBUCK) bucketStart[t] = acc - v;
}

__global__ void __launch_bounds__(256) k_bin2(
    const int* __restrict__ ei, const int* __restrict__ bucketStart,
    const int* __restrict__ blockoff, unsigned int* __restrict__ bucketed)
{
    __shared__ int cur[NBUCK];
    const int t = threadIdx.x;
    for (int i = t; i < NBUCK; i += 256)
        cur[i] = bucketStart[i] + blockoff[blockIdx.x * NBUCK + i];
    __syncthreads();
    const int e0 = blockIdx.x * CHUNK;
    for (int i = t; i < CHUNK; i += 256) {
        int e = e0 + i;
        if (e < E_TOT) {
            int src = (e < N_EDGES) ? ei[e] : (e - N_EDGES);
            int dst = (e < N_EDGES) ? ei[N_EDGES + e] : (e - N_EDGES);
            int b = dst >> BSH;
            int p = atomicAdd(&cur[b], 1);
            bucketed[p] = (unsigned)src | ((unsigned)(dst & (BSIZE - 1)) << 17);
        }
    }
}

__global__ void __launch_bounds__(256) k_bhist(
    const unsigned int* __restrict__ bucketed,
    const int* __restrict__ bucketStart, const int* __restrict__ bucketCount,
    int* __restrict__ deg, int* __restrict__ rowptr, int* __restrict__ bucketPad)
{
    __shared__ int hist[BSIZE];
    __shared__ int sh[256];
    const int t = threadIdx.x;
    const int b = blockIdx.x;
    hist[t] = 0; hist[t + 256] = 0;
    __syncthreads();
    const int beg = bucketStart[b], cnt = bucketCount[b];
    for (int i = t; i < cnt; i += 256)
        atomicAdd(&hist[bucketed[beg + i] >> 17], 1);
    __syncthreads();
    int h0 = hist[2 * t], h1 = hist[2 * t + 1];
    int a = (h0 + 7) & ~7, c = (h1 + 7) & ~7;
    int s = a + c;
    sh[t] = s; __syncthreads();
    for (int off = 1; off < 256; off <<= 1) {
        int add = (t >= off) ? sh[t - off] : 0;
        __syncthreads();
        s += add; sh[t] = s; __syncthreads();
    }
    int base = s - a - c;
    const int n0 = b * BSIZE;
    int na = n0 + 2 * t, nb = n0 + 2 * t + 1;
    if (na < N_NODES) { deg[na] = h0; rowptr[na] = base; }
    if (nb < N_NODES) { deg[nb] = h1; rowptr[nb] = base + a; }
    if (t == 255) bucketPad[b] = s;
}

__global__ void k_bscan2(const int* __restrict__ bucketPad, int* __restrict__ bucketBase,
                         int* __restrict__ rowptr)
{
    __shared__ int sh[256];
    int t = threadIdx.x;
    int v = (t < NBUCK) ? bucketPad[t] : 0;
    int acc = v;
    sh[t] = acc; __syncthreads();
    for (int off = 1; off < 256; off <<= 1) {
        int add = (t >= off) ? sh[t - off] : 0;
        __syncthreads();
        acc += add; sh[t] = acc; __syncthreads();
    }
    if (t < NBUCK) bucketBase[t] = acc - v;
    if (t == NBUCK - 1) rowptr[N_NODES] = acc;
}

// P4c: finalize rowptr, scatter srcs via LDS cursors, mark pads with -1
__global__ void __launch_bounds__(256) k_bscat(
    const unsigned int* __restrict__ bucketed,
    const int* __restrict__ bucketStart, const int* __restrict__ bucketCount,
    const int* __restrict__ bucketBase, const int* __restrict__ bucketPad,
    int* __restrict__ rowptr, int* __restrict__ srcs)
{
    __shared__ int cur[BSIZE];
    const int t = threadIdx.x;
    const int b = blockIdx.x;
    const int base = bucketBase[b];
    const int n0 = b * BSIZE;
    #pragma unroll
    for (int k = 0; k < 2; ++k) {
        int nl = t + k * 256;
        int n = n0 + nl;
        if (n < N_NODES) {
            int r = rowptr[n] + base;
            rowptr[n] = r;
            cur[nl] = r;
        }
    }
    __syncthreads();
    const int beg = bucketStart[b], cnt = bucketCount[b];
    for (int i = t; i < cnt; i += 256) {
        unsigned p = bucketed[beg + i];
        int rank = atomicAdd(&cur[p >> 17], 1);
        srcs[rank] = (int)(p & 0x1FFFFu);
    }
    __syncthreads();
    const int bend = base + bucketPad[b];
    #pragma unroll
    for (int k = 0; k < 2; ++k) {
        int nl = t + k * 256;
        int n = n0 + nl;
        if (n < N_NODES) {
            int e = (nl == BSIZE - 1 || n == N_NODES - 1) ? bend : rowptr[n + 1];
            for (int j = cur[nl]; j < e; ++j) srcs[j] = -1;   // pad sentinel
        }
    }
}

// ---------------------------------------------------------------------------
// Layer-1 aggregation in x-space (16 lanes per node, one edge per lane)
// ---------------------------------------------------------------------------
__global__ void __launch_bounds__(256) k_gather1x(
    const int* __restrict__ srcs, const int* __restrict__ rowptr, const int* __restrict__ deg,
    const float* __restrict__ x,
    const float* __restrict__ A1c, const float* __restrict__ D1c,
    float4* __restrict__ agg0, float4* __restrict__ agg1, float2* __restrict__ wsA)
{
    const int tid  = threadIdx.x;
    const int n    = blockIdx.x * 16 + (tid >> 4);
    const int lane = tid & 15;
    if (n >= N_NODES) return;

    const float4 A0 = ((const float4*)A1c)[0], A1v = ((const float4*)A1c)[1];
    const float4 D0 = ((const float4*)D1c)[0], D1v = ((const float4*)D1c)[1];
    const float4 xn = ((const float4*)x)[n];
    const float ad0 = xn.x * D0.x + xn.y * D0.y + xn.z * D0.z + xn.w * D0.w;
    const float ad1 = xn.x * D1v.x + xn.y * D1v.y + xn.z * D1v.z + xn.w * D1v.w;

    const int beg = rowptr[n], rend = beg + deg[n];
    float4 acc0 = {0.f, 0.f, 0.f, 0.f}, acc1 = {0.f, 0.f, 0.f, 0.f};
    float ws0 = 0.f, ws1 = 0.f;
    for (int j = beg + lane; j < rend; j += 16) {
        const int s = srcs[j];
        const float4 xs = ((const float4*)x)[s];
        const float as0 = xs.x * A0.x + xs.y * A0.y + xs.z * A0.z + xs.w * A0.w;
        const float as1 = xs.x * A1v.x + xs.y * A1v.y + xs.z * A1v.z + xs.w * A1v.w;
        const float w0 = __expf(lrelu(as0 + ad0));
        const float w1 = __expf(lrelu(as1 + ad1));
        acc0.x = fmaf(w0, xs.x, acc0.x); acc0.y = fmaf(w0, xs.y, acc0.y);
        acc0.z = fmaf(w0, xs.z, acc0.z); acc0.w = fmaf(w0, xs.w, acc0.w);
        acc1.x = fmaf(w1, xs.x, acc1.x); acc1.y = fmaf(w1, xs.y, acc1.y);
        acc1.z = fmaf(w1, xs.z, acc1.z); acc1.w = fmaf(w1, xs.w, acc1.w);
        ws0 += w0; ws1 += w1;
    }
    #pragma unroll
    for (int off = 1; off < 16; off <<= 1) {
        acc0.x += __shfl_xor(acc0.x, off, 64);
        acc0.y += __shfl_xor(acc0.y, off, 64);
        acc0.z += __shfl_xor(acc0.z, off, 64);
        acc0.w += __shfl_xor(acc0.w, off, 64);
        acc1.x += __shfl_xor(acc1.x, off, 64);
        acc1.y += __shfl_xor(acc1.y, off, 64);
        acc1.z += __shfl_xor(acc1.z, off, 64);
        acc1.w += __shfl_xor(acc1.w, off, 64);
        ws0    += __shfl_xor(ws0,    off, 64);
        ws1    += __shfl_xor(ws1,    off, 64);
    }
    if (lane == 0) {
        agg0[n] = acc0;
        agg1[n] = acc1;
        wsA[n]  = make_float2(ws0, ws1);
    }
}

// ---------------------------------------------------------------------------
// k_h2f: out1 built as fp16 in LDS, as2/ad2 reduction, MFMA GEMM -> h2 fp16
// ---------------------------------------------------------------------------
#define H2_NPB 64
#define SROW_H_LD 136
__global__ void __launch_bounds__(256) k_h2f(
    const float4* __restrict__ agg0, const float4* __restrict__ agg1,
    const float2* __restrict__ wsA,
    const float* __restrict__ w1, const float* __restrict__ b1,
    const __half* __restrict__ w2frag,
    const float* __restrict__ B2, const float* __restrict__ E2,
    __half* __restrict__ h2h, float* __restrict__ as2, float* __restrict__ ad2)
{
    __shared__ __align__(16) _Float16 srow[H2_NPB * SROW_H_LD];
    const int tid = threadIdx.x;
    const int bn  = blockIdx.x * H2_NPB;

    #pragma unroll 4
    for (int t = 0; t < 16; ++t) {
        int i = tid + t * 256;
        int r = i >> 6, c2 = i & 63;
        int n = bn + r;
        int head = c2 >> 5;
        float4 a; float ws;
        if (n < N_NODES) {
            a = head ? agg1[n] : agg0[n];
            float2 w = wsA[n];
            ws = head ? w.y : w.x;
        } else { a = make_float4(0.f, 0.f, 0.f, 0.f); ws = 1.f; }
        const float4 wA = ((const float4*)w1)[2 * c2];
        const float4 wB = ((const float4*)w1)[2 * c2 + 1];
        const float2 bb = ((const float2*)b1)[c2];
        float inv = 1.f / ws;
        float v0 = elu_f((a.x * wA.x + a.y * wA.y + a.z * wA.z + a.w * wA.w) * inv + bb.x);
        float v1 = elu_f((a.x * wB.x + a.y * wB.y + a.z * wB.z + a.w * wB.w) * inv + bb.y);
        *(__half2*)&srow[r * SROW_H_LD + 2 * c2] = __floats2half2_rn(v0, v1);
    }
    __syncthreads();

    {
        int r = tid >> 2, q = tid & 3;
        const __half2* row = (const __half2*)&srow[r * SROW_H_LD];
        float ps = 0.f, pd = 0.f;
        #pragma unroll 4
        for (int i = 0; i < 16; ++i) {
            int c2 = q * 16 + i;
            float2 v  = __half22float2(row[c2]);
            float2 Bv = ((const float2*)B2)[c2];
            float2 Ev = ((const float2*)E2)[c2];
            ps += v.x * Bv.x + v.y * Bv.y;
            pd += v.x * Ev.x + v.y * Ev.y;
        }
        ps += __shfl_xor(ps, 1, 64); ps += __shfl_xor(ps, 2, 64);
        pd += __shfl_xor(pd, 1, 64); pd += __shfl_xor(pd, 2, 64);
        int n = bn + r;
        if (q == 0 && n < N_NODES) { as2[n] = ps; ad2[n] = pd; }
    }

    const int lane = tid & 63;
    const int wv   = tid >> 6;
    const int mrow = lane & 15;
    const int kc   = lane >> 4;
    f32x4 acc[4] = {{0.f,0.f,0.f,0.f},{0.f,0.f,0.f,0.f},{0.f,0.f,0.f,0.f},{0.f,0.f,0.f,0.f}};
    const half8* __restrict__ wf = (const half8*)w2frag;
    #pragma unroll
    for (int ks = 0; ks < 4; ++ks) {
        const half8 af = *(const half8*)&srow[(wv * 16 + mrow) * SROW_H_LD + ks * 32 + kc * 8];
        #pragma unroll
        for (int nt = 0; nt < 4; ++nt) {
            const half8 bf = wf[(nt * 4 + ks) * 64 + lane];
            acc[nt] = __builtin_amdgcn_mfma_f32_16x16x32_f16(af, bf, acc[nt], 0, 0, 0);
        }
    }
    #pragma unroll
    for (int nt = 0; nt < 4; ++nt) {
        #pragma unroll
        for (int reg = 0; reg < 4; ++reg) {
            int node = bn + wv * 16 + ((lane >> 4) << 2) + reg;
            int dim  = nt * 16 + (lane & 15);
            if (node < N_NODES) h2h[(size_t)node * 64 + dim] = __float2half(acc[nt][reg]);
        }
    }
}

// ---------------------------------------------------------------------------
// Gather layer 2, 8-edge-parallel, packed fp16 accumulation, INLINE weights:
// w = exp(lrelu(as2[s] + ad2[n])) computed per edge (all dq lanes redundant —
// issue-slot cost only; round-11 A/B showed gather2 is not VALU-bound).
// Pad slots carry srcs = -1 -> w = 0.
// ---------------------------------------------------------------------------
__global__ void __launch_bounds__(256) k_gather2(
    const int* __restrict__ srcs, const int* __restrict__ rowptr,
    const float* __restrict__ as2, const float* __restrict__ ad2,
    const _Float16* __restrict__ h2h, const float* __restrict__ b2,
    float* __restrict__ out2)
{
    const int tid  = threadIdx.x;
    const int n    = blockIdx.x * 4 + (tid >> 6);   // N_NODES % 4 == 0
    const int lane = tid & 63;
    const int eg   = lane >> 3;
    const int dq   = lane & 7;
    const int beg = rowptr[n], end = rowptr[n + 1];
    const float adv = ad2[n];

    half8 hacc = {0, 0, 0, 0, 0, 0, 0, 0};
    float wsum = 0.f;
    for (int j = beg + eg; j < end; j += 8) {
        const int s = srcs[j];
        const int sa = (s >= 0) ? s : 0;
        float w = 0.f;
        if (s >= 0) w = __expf(lrelu(as2[s] + adv));
        const half8 v = *(const half8*)&h2h[(size_t)sa * 64 + dq * 8];
        const _Float16 wh = (_Float16)w;
        const half8 ws8 = {wh, wh, wh, wh, wh, wh, wh, wh};
        hacc += v * ws8;                  // 4x v_pk_fma_f16
        wsum += w;
    }
    float a0 = (float)hacc[0], a1 = (float)hacc[1], a2 = (float)hacc[2], a3 = (float)hacc[3];
    float a4 = (float)hacc[4], a5 = (float)hacc[5], a6 = (float)hacc[6], a7 = (float)hacc[7];
    #pragma unroll
    for (int off = 8; off < 64; off <<= 1) {
        a0 += __shfl_xor(a0, off, 64);
        a1 += __shfl_xor(a1, off, 64);
        a2 += __shfl_xor(a2, off, 64);
        a3 += __shfl_xor(a3, off, 64);
        a4 += __shfl_xor(a4, off, 64);
        a5 += __shfl_xor(a5, off, 64);
        a6 += __shfl_xor(a6, off, 64);
        a7 += __shfl_xor(a7, off, 64);
        wsum += __shfl_xor(wsum, off, 64);
    }
    if (eg == 0) {
        const float inv = 1.f / wsum;
        const float4 bA = ((const float4*)b2)[dq * 2];
        const float4 bB = ((const float4*)b2)[dq * 2 + 1];
        float4 oA, oB;
        oA.x = elu_f(a0 * inv + bA.x);
        oA.y = elu_f(a1 * inv + bA.y);
        oA.z = elu_f(a2 * inv + bA.z);
        oA.w = elu_f(a3 * inv + bA.w);
        oB.x = elu_f(a4 * inv + bB.x);
        oB.y = elu_f(a5 * inv + bB.y);
        oB.z = elu_f(a6 * inv + bB.z);
        oB.w = elu_f(a7 * inv + bB.w);
        float4* orow = (float4*)(out2 + (size_t)n * 64);
        orow[dq * 2]     = oA;
        orow[dq * 2 + 1] = oB;
    }
}

// ---------------------------------------------------------------------------
// Global mean pool: batch sorted -> register runs, flush at boundaries
// ---------------------------------------------------------------------------
__global__ void __launch_bounds__(256) k_pool(
    const float* __restrict__ out2, const int* __restrict__ batch,
    float* __restrict__ pool, float* __restrict__ cnt)
{
    const int wv = threadIdx.x >> 6, d = threadIdx.x & 63;
    const int wid = blockIdx.x * 4 + wv;
    const int per = (N_NODES + 2047) / 2048;
    int n0 = wid * per, n1 = min(n0 + per, N_NODES);
    if (n0 >= n1) return;
    float acc = 0.f; int g = batch[n0]; int run = 0;
    for (int n = n0; n < n1; ++n) {
        int gn = batch[n];
        if (gn != g) {
            atomicAdd(&pool[g * 64 + d], acc);
            if (d == 0) atomicAdd(&cnt[g], (float)run);
            acc = 0.f; run = 0; g = gn;
        }
        acc += out2[(size_t)n * 64 + d];
        ++run;
    }
    atomicAdd(&pool[g * 64 + d], acc);
    if (d == 0) atomicAdd(&cnt[g], (float)run);
}

__global__ void k_head(const float* __restrict__ pool, const float* __restrict__ cnt,
                       const float* __restrict__ wp, const float* __restrict__ bp,
                       float* __restrict__ out)
{
    int t = threadIdx.x;
    int g = t >> 4, s = t & 15;
    float c = cnt[g]; if (c < 1.f) c = 1.f;
    float acc = bp[s];
    for (int d = 0; d < 64; ++d) acc += (pool[g * 64 + d] / c) * wp[s * 64 + d];
    out[g * 16 + s] = acc;
}

extern "C" void kernel_launch(void* const* d_in, const int* in_sizes, int n_in,
                              void* d_out, int out_size, void* d_ws, size_t ws_size,
                              hipStream_t stream)
{
    const float* x     = (const float*)d_in[0];
    const int*   ei    = (const int*)  d_in[1];
    const int*   batch = (const int*)  d_in[2];
    const float* w1    = (const float*)d_in[3];
    const float* asr1  = (const float*)d_in[4];
    const float* adr1  = (const float*)d_in[5];
    const float* b1    = (const float*)d_in[6];
    const float* w2    = (const float*)d_in[7];
    const float* asr2  = (const float*)d_in[8];
    const float* adr2  = (const float*)d_in[9];
    const float* b2    = (const float*)d_in[10];
    const float* wp    = (const float*)d_in[11];
    const float* bp    = (const float*)d_in[12];
    float* out = (float*)d_out;

    // Workspace layout (~58 MB)
    float4* agg0 = (float4*)d_ws;                          // N
    float4* agg1 = agg0 + N_NODES;                         // N
    float2* wsA  = (float2*)(agg1 + N_NODES);              // N
    __half* h2h  = (__half*)(wsA + N_NODES);               // N*64 fp16 (16B-aligned)
    float* out2  = (float*)(h2h + (size_t)N_NODES * 64);   // N*64 f32 (16B-aligned)
    float* as2   = out2 + (size_t)N_NODES * 64;            // N
    float* ad2   = as2 + N_NODES;                          // N
    float* pool  = ad2 + N_NODES;                          // 64*64 (+cnt contiguous)
    float* cnt   = pool + N_GRAPHS * 64;                   // 64
    int* deg     = (int*)(cnt + N_GRAPHS);                 // N
    int* rowptr  = deg + N_NODES;                          // N+1
    unsigned int* bucketed = (unsigned int*)(rowptr + N_NODES + 1); // E_TOT
    int* srcs    = (int*)(bucketed + E_TOT);               // E_CAP
    int* blockoff    = srcs + E_CAP;                       // NBLKS*NBUCK
    int* bucketCount = blockoff + NBLKS * NBUCK;           // NBUCK
    int* bucketStart = bucketCount + NBUCK;                // NBUCK
    int* bucketPad   = bucketStart + NBUCK;                // NBUCK
    int* bucketBase  = bucketPad + NBUCK;                  // NBUCK
    float* A1    = (float*)(bucketBase + NBUCK);           // 8
    float* D1    = A1 + 8;                                 // 8
    float* B2    = D1 + 8;                                 // 128
    float* E2    = B2 + 128;                               // 128
    __half* w2frag = (__half*)(((uintptr_t)(E2 + 128) + 15) & ~(uintptr_t)15); // 8192 fp16

    // Folded projections + fragment W2 + zero bucketCount/pool/cnt (merged)
    k_preall<<<33, 256, 0, stream>>>(w1, asr1, adr1, w2, asr2, adr2,
                                     A1, D1, B2, E2, w2frag, bucketCount, pool);

    // Counting-sort CSR build (padded x8, pad sentinel -1, no per-edge global atomics)
    k_bin1 <<<NBLKS, 256, 0, stream>>>(ei, bucketCount, blockoff);
    k_bscan<<<1, 256, 0, stream>>>(bucketCount, bucketStart);
    k_bin2 <<<NBLKS, 256, 0, stream>>>(ei, bucketStart, blockoff, bucketed);
    k_bhist<<<NBUCK, 256, 0, stream>>>(bucketed, bucketStart, bucketCount, deg, rowptr, bucketPad);
    k_bscan2<<<1, 256, 0, stream>>>(bucketPad, bucketBase, rowptr);
    k_bscat<<<NBUCK, 256, 0, stream>>>(bucketed, bucketStart, bucketCount, bucketBase,
                                       bucketPad, rowptr, srcs);

    // Layer-1 aggregation in x-space
    const int gb = (N_NODES + 15) / 16;
    k_gather1x<<<gb, 256, 0, stream>>>(srcs, rowptr, deg, x, A1, D1, agg0, agg1, wsA);

    // Fused out1-build + as2/ad2 + layer-2 GEMM (MFMA)
    k_h2f<<<(N_NODES + H2_NPB - 1) / H2_NPB, 256, 0, stream>>>(
        agg0, agg1, wsA, w1, b1, w2frag, B2, E2, h2h, as2, ad2);

    // Layer-2 aggregate with inline weights (weights2 kernel deleted)
    k_gather2<<<N_NODES / 4, 256, 0, stream>>>(srcs, rowptr, as2, ad2,
                                               (const _Float16*)h2h, b2, out2);

    // Mean pool + head
    k_pool<<<512, 256, 0, stream>>>(out2, batch, pool, cnt);
    k_head<<<1, 1024, 0, stream>>>(pool, cnt, wp, bp, out);
}

// Round 16
// 195.599 us; speedup vs baseline: 1.4852x; 1.0098x over previous
//
#include <hip/hip_runtime.h>
#include <hip/hip_fp16.h>

#define N_NODES  100000
#define N_EDGES  1000000
#define E_TOT    1100000   // edges + self-loops
#define E_CAP    1900000   // padded-CSR capacity (deg padded to x8: <= E_TOT + 7*N)
#define N_GRAPHS 64

// counting-sort CSR parameters
#define BSH    9
#define BSIZE  512                                   // nodes per bucket
#define NBUCK  ((N_NODES + BSIZE - 1) / BSIZE)       // 196
#define CHUNK  4096
#define NBLKS  ((E_TOT + CHUNK - 1) / CHUNK)         // 269

typedef _Float16 half8 __attribute__((ext_vector_type(8)));
typedef float    f32x4 __attribute__((ext_vector_type(4)));

__device__ __forceinline__ float elu_f(float v) {
    return v > 0.f ? v : expm1f(v);
}

__device__ __forceinline__ float lrelu(float v) {
    return v > 0.f ? v : 0.2f * v;
}

__device__ __forceinline__ int lbound(const int* __restrict__ a, int n, int v) {
    int lo = 0, hi = n;
    while (lo < hi) { int m = (lo + hi) >> 1; if (a[m] < v) lo = m + 1; else hi = m; }
    return lo;
}

// ---------------------------------------------------------------------------
// k_preall: block 0 = folded attention projections + zero bucketCount +
//           cnt[g] via binary search on sorted batch;
//           blocks 1..32 = fragment-ordered fp16 W2 (+ zero pool).
// ---------------------------------------------------------------------------
__global__ void k_preall(const float* __restrict__ w1,
                         const float* __restrict__ as1v, const float* __restrict__ ad1v,
                         const float* __restrict__ w2,
                         const float* __restrict__ as2v, const float* __restrict__ ad2v,
                         float* __restrict__ A1, float* __restrict__ D1,
                         float* __restrict__ B2, float* __restrict__ E2,
                         __half* __restrict__ w2frag,
                         int* __restrict__ bucketCount, float* __restrict__ pool,
                         const int* __restrict__ batch, float* __restrict__ cnt)
{
    if (blockIdx.x == 0) {
        int t = threadIdx.x;
        if (t < 128) {
            float acc = 0.f;
            for (int d = 0; d < 64; ++d) acc += w2[d * 128 + t] * as2v[d];
            B2[t] = acc;
        } else {
            int k = t - 128;
            float acc = 0.f;
            for (int d = 0; d < 64; ++d) acc += w2[d * 128 + k] * ad2v[d];
            E2[k] = acc;
        }
        if (t < 8) {
            int h = t >> 2, k = t & 3;
            float acc = 0.f;
            for (int d = 0; d < 64; ++d) acc += w1[(h * 64 + d) * 4 + k] * as1v[h * 64 + d];
            A1[t] = acc;
        } else if (t < 16) {
            int i = t - 8, h = i >> 2, k = i & 3;
            float acc = 0.f;
            for (int d = 0; d < 64; ++d) acc += w1[(h * 64 + d) * 4 + k] * ad1v[h * 64 + d];
            D1[i] = acc;
        }
        if (t < NBUCK) bucketCount[t] = 0;
        if (t < N_GRAPHS) {
            int a = lbound(batch, N_NODES, t);
            int b = lbound(batch, N_NODES, t + 1);
            cnt[t] = (float)(b - a);
        }
    } else {
        int f = (blockIdx.x - 1) * 256 + threadIdx.x;  // 8192 total
        int j = f & 7, ln = (f >> 3) & 63, g = f >> 9; // g = nt*4+ks
        int nt = g >> 2, ks = g & 3;
        int col = nt * 16 + (ln & 15);
        int k   = ks * 32 + ((ln >> 4) << 3) + j;
        w2frag[f] = __float2half(w2[col * 128 + k]);
        if (f < N_GRAPHS * 64) pool[f] = 0.f;          // pool only; cnt written above
    }
}

// ---------------------------------------------------------------------------
// Counting-sort CSR build — no per-edge global atomics.
// P1: per-block LDS bucket histogram; reserve per-(block,bucket) offsets.
// ---------------------------------------------------------------------------
__global__ void __launch_bounds__(256) k_bin1(
    const int* __restrict__ ei, int* __restrict__ bucketCount, int* __restrict__ blockoff)
{
    __shared__ int hist[NBUCK];
    const int t = threadIdx.x;
    for (int i = t; i < NBUCK; i += 256) hist[i] = 0;
    __syncthreads();
    const int e0 = blockIdx.x * CHUNK;
    for (int i = t; i < CHUNK; i += 256) {
        int e = e0 + i;
        if (e < E_TOT) {
            int dst = (e < N_EDGES) ? ei[N_EDGES + e] : (e - N_EDGES);
            atomicAdd(&hist[dst >> BSH], 1);
        }
    }
    __syncthreads();
    for (int i = t; i < NBUCK; i += 256)
        blockoff[blockIdx.x * NBUCK + i] = atomicAdd(&bucketCount[i], hist[i]);
}

// P2 (scan fused): each block scans bucketCount in LDS; block 0 also
// materializes bucketStart for bhist/bscat. Then scatter packed keys.
__global__ void __launch_bounds__(256) k_bin2(
    const int* __restrict__ ei, const int* __restrict__ bucketCount,
    const int* __restrict__ blockoff, int* __restrict__ bucketStart,
    unsigned int* __restrict__ bucketed)
{
    __shared__ int sh[256];
    __shared__ int cur[NBUCK];
    const int t = threadIdx.x;
    int v = (t < NBUCK) ? bucketCount[t] : 0;
    int acc = v;
    sh[t] = acc; __syncthreads();
    for (int off = 1; off < 256; off <<= 1) {
        int add = (t >= off) ? sh[t - off] : 0;
        __syncthreads();
        acc += add; sh[t] = acc; __syncthreads();
    }
    if (t < NBUCK) {
        int st = acc - v;                               // exclusive
        cur[t] = st + blockoff[blockIdx.x * NBUCK + t];
        if (blockIdx.x == 0) bucketStart[t] = st;
    }
    __syncthreads();
    const int e0 = blockIdx.x * CHUNK;
    for (int i = t; i < CHUNK; i += 256) {
        int e = e0 + i;
        if (e < E_TOT) {
            int src = (e < N_EDGES) ? ei[e] : (e - N_EDGES);
            int dst = (e < N_EDGES) ? ei[N_EDGES + e] : (e - N_EDGES);
            int b = dst >> BSH;
            int p = atomicAdd(&cur[b], 1);
            bucketed[p] = (unsigned)src | ((unsigned)(dst & (BSIZE - 1)) << 17);
        }
    }
}

// P4a: per-bucket LDS histogram -> deg; padded exclusive scan -> local rowptr;
//      padded bucket total -> bucketPad
__global__ void __launch_bounds__(256) k_bhist(
    const unsigned int* __restrict__ bucketed,
    const int* __restrict__ bucketStart, const int* __restrict__ bucketCount,
    int* __restrict__ deg, int* __restrict__ rowptr, int* __restrict__ bucketPad)
{
    __shared__ int hist[BSIZE];
    __shared__ int sh[256];
    const int t = threadIdx.x;
    const int b = blockIdx.x;
    hist[t] = 0; hist[t + 256] = 0;
    __syncthreads();
    const int beg = bucketStart[b], cnt = bucketCount[b];
    for (int i = t; i < cnt; i += 256)
        atomicAdd(&hist[bucketed[beg + i] >> 17], 1);
    __syncthreads();
    int h0 = hist[2 * t], h1 = hist[2 * t + 1];
    int a = (h0 + 7) & ~7, c = (h1 + 7) & ~7;
    int s = a + c;
    sh[t] = s; __syncthreads();
    for (int off = 1; off < 256; off <<= 1) {
        int add = (t >= off) ? sh[t - off] : 0;
        __syncthreads();
        s += add; sh[t] = s; __syncthreads();
    }
    int base = s - a - c;
    const int n0 = b * BSIZE;
    int na = n0 + 2 * t, nb = n0 + 2 * t + 1;
    if (na < N_NODES) { deg[na] = h0; rowptr[na] = base; }
    if (nb < N_NODES) { deg[nb] = h1; rowptr[nb] = base + a; }
    if (t == 255) bucketPad[b] = s;
}

// P4c (scan fused): each block scans bucketPad in LDS for its own base;
// finalize rowptr, scatter srcs via LDS cursors, mark pads with -1.
__global__ void __launch_bounds__(256) k_bscat(
    const unsigned int* __restrict__ bucketed,
    const int* __restrict__ bucketStart, const int* __restrict__ bucketCount,
    const int* __restrict__ bucketPad,
    int* __restrict__ rowptr, int* __restrict__ srcs)
{
    __shared__ int sh[256];
    __shared__ int excl[NBUCK];
    __shared__ int cur[BSIZE];
    const int t = threadIdx.x;
    const int b = blockIdx.x;

    // in-block exclusive scan of bucketPad
    int v = (t < NBUCK) ? bucketPad[t] : 0;
    int acc = v;
    sh[t] = acc; __syncthreads();
    for (int off = 1; off < 256; off <<= 1) {
        int add = (t >= off) ? sh[t - off] : 0;
        __syncthreads();
        acc += add; sh[t] = acc; __syncthreads();
    }
    if (t < NBUCK) excl[t] = acc - v;
    if (b == 0 && t == NBUCK - 1) rowptr[N_NODES] = acc;   // grand padded total
    __syncthreads();
    const int base = excl[b];

    const int n0 = b * BSIZE;
    #pragma unroll
    for (int k = 0; k < 2; ++k) {
        int nl = t + k * 256;
        int n = n0 + nl;
        if (n < N_NODES) {
            int r = rowptr[n] + base;
            rowptr[n] = r;
            cur[nl] = r;
        }
    }
    __syncthreads();
    const int beg = bucketStart[b], cnt = bucketCount[b];
    for (int i = t; i < cnt; i += 256) {
        unsigned p = bucketed[beg + i];
        int rank = atomicAdd(&cur[p >> 17], 1);
        srcs[rank] = (int)(p & 0x1FFFFu);
    }
    __syncthreads();
    const int bend = base + bucketPad[b];
    #pragma unroll
    for (int k = 0; k < 2; ++k) {
        int nl = t + k * 256;
        int n = n0 + nl;
        if (n < N_NODES) {
            int e = (nl == BSIZE - 1 || n == N_NODES - 1) ? bend : rowptr[n + 1];
            for (int j = cur[nl]; j < e; ++j) srcs[j] = -1;   // pad sentinel
        }
    }
}

// ---------------------------------------------------------------------------
// Layer-1 aggregation in x-space (16 lanes per node, one edge per lane)
// ---------------------------------------------------------------------------
__global__ void __launch_bounds__(256) k_gather1x(
    const int* __restrict__ srcs, const int* __restrict__ rowptr, const int* __restrict__ deg,
    const float* __restrict__ x,
    const float* __restrict__ A1c, const float* __restrict__ D1c,
    float4* __restrict__ agg0, float4* __restrict__ agg1, float2* __restrict__ wsA)
{
    const int tid  = threadIdx.x;
    const int n    = blockIdx.x * 16 + (tid >> 4);
    const int lane = tid & 15;
    if (n >= N_NODES) return;

    const float4 A0 = ((const float4*)A1c)[0], A1v = ((const float4*)A1c)[1];
    const float4 D0 = ((const float4*)D1c)[0], D1v = ((const float4*)D1c)[1];
    const float4 xn = ((const float4*)x)[n];
    const float ad0 = xn.x * D0.x + xn.y * D0.y + xn.z * D0.z + xn.w * D0.w;
    const float ad1 = xn.x * D1v.x + xn.y * D1v.y + xn.z * D1v.z + xn.w * D1v.w;

    const int beg = rowptr[n], rend = beg + deg[n];
    float4 acc0 = {0.f, 0.f, 0.f, 0.f}, acc1 = {0.f, 0.f, 0.f, 0.f};
    float ws0 = 0.f, ws1 = 0.f;
    for (int j = beg + lane; j < rend; j += 16) {
        const int s = srcs[j];
        const float4 xs = ((const float4*)x)[s];
        const float as0 = xs.x * A0.x + xs.y * A0.y + xs.z * A0.z + xs.w * A0.w;
        const float as1 = xs.x * A1v.x + xs.y * A1v.y + xs.z * A1v.z + xs.w * A1v.w;
        const float w0 = __expf(lrelu(as0 + ad0));
        const float w1 = __expf(lrelu(as1 + ad1));
        acc0.x = fmaf(w0, xs.x, acc0.x); acc0.y = fmaf(w0, xs.y, acc0.y);
        acc0.z = fmaf(w0, xs.z, acc0.z); acc0.w = fmaf(w0, xs.w, acc0.w);
        acc1.x = fmaf(w1, xs.x, acc1.x); acc1.y = fmaf(w1, xs.y, acc1.y);
        acc1.z = fmaf(w1, xs.z, acc1.z); acc1.w = fmaf(w1, xs.w, acc1.w);
        ws0 += w0; ws1 += w1;
    }
    #pragma unroll
    for (int off = 1; off < 16; off <<= 1) {
        acc0.x += __shfl_xor(acc0.x, off, 64);
        acc0.y += __shfl_xor(acc0.y, off, 64);
        acc0.z += __shfl_xor(acc0.z, off, 64);
        acc0.w += __shfl_xor(acc0.w, off, 64);
        acc1.x += __shfl_xor(acc1.x, off, 64);
        acc1.y += __shfl_xor(acc1.y, off, 64);
        acc1.z += __shfl_xor(acc1.z, off, 64);
        acc1.w += __shfl_xor(acc1.w, off, 64);
        ws0    += __shfl_xor(ws0,    off, 64);
        ws1    += __shfl_xor(ws1,    off, 64);
    }
    if (lane == 0) {
        agg0[n] = acc0;
        agg1[n] = acc1;
        wsA[n]  = make_float2(ws0, ws1);
    }
}

// ---------------------------------------------------------------------------
// k_h2f: out1 built as fp16 in LDS, as2/ad2 reduction, MFMA GEMM -> h2 fp16
// ---------------------------------------------------------------------------
#define H2_NPB 64
#define SROW_H_LD 136
__global__ void __launch_bounds__(256) k_h2f(
    const float4* __restrict__ agg0, const float4* __restrict__ agg1,
    const float2* __restrict__ wsA,
    const float* __restrict__ w1, const float* __restrict__ b1,
    const __half* __restrict__ w2frag,
    const float* __restrict__ B2, const float* __restrict__ E2,
    __half* __restrict__ h2h, float* __restrict__ as2, float* __restrict__ ad2)
{
    __shared__ __align__(16) _Float16 srow[H2_NPB * SROW_H_LD];
    const int tid = threadIdx.x;
    const int bn  = blockIdx.x * H2_NPB;

    #pragma unroll 4
    for (int t = 0; t < 16; ++t) {
        int i = tid + t * 256;
        int r = i >> 6, c2 = i & 63;
        int n = bn + r;
        int head = c2 >> 5;
        float4 a; float ws;
        if (n < N_NODES) {
            a = head ? agg1[n] : agg0[n];
            float2 w = wsA[n];
            ws = head ? w.y : w.x;
        } else { a = make_float4(0.f, 0.f, 0.f, 0.f); ws = 1.f; }
        const float4 wA = ((const float4*)w1)[2 * c2];
        const float4 wB = ((const float4*)w1)[2 * c2 + 1];
        const float2 bb = ((const float2*)b1)[c2];
        float inv = 1.f / ws;
        float v0 = elu_f((a.x * wA.x + a.y * wA.y + a.z * wA.z + a.w * wA.w) * inv + bb.x);
        float v1 = elu_f((a.x * wB.x + a.y * wB.y + a.z * wB.z + a.w * wB.w) * inv + bb.y);
        *(__half2*)&srow[r * SROW_H_LD + 2 * c2] = __floats2half2_rn(v0, v1);
    }
    __syncthreads();

    {
        int r = tid >> 2, q = tid & 3;
        const __half2* row = (const __half2*)&srow[r * SROW_H_LD];
        float ps = 0.f, pd = 0.f;
        #pragma unroll 4
        for (int i = 0; i < 16; ++i) {
            int c2 = q * 16 + i;
            float2 v  = __half22float2(row[c2]);
            float2 Bv = ((const float2*)B2)[c2];
            float2 Ev = ((const float2*)E2)[c2];
            ps += v.x * Bv.x + v.y * Bv.y;
            pd += v.x * Ev.x + v.y * Ev.y;
        }
        ps += __shfl_xor(ps, 1, 64); ps += __shfl_xor(ps, 2, 64);
        pd += __shfl_xor(pd, 1, 64); pd += __shfl_xor(pd, 2, 64);
        int n = bn + r;
        if (q == 0 && n < N_NODES) { as2[n] = ps; ad2[n] = pd; }
    }

    const int lane = tid & 63;
    const int wv   = tid >> 6;
    const int mrow = lane & 15;
    const int kc   = lane >> 4;
    f32x4 acc[4] = {{0.f,0.f,0.f,0.f},{0.f,0.f,0.f,0.f},{0.f,0.f,0.f,0.f},{0.f,0.f,0.f,0.f}};
    const half8* __restrict__ wf = (const half8*)w2frag;
    #pragma unroll
    for (int ks = 0; ks < 4; ++ks) {
        const half8 af = *(const half8*)&srow[(wv * 16 + mrow) * SROW_H_LD + ks * 32 + kc * 8];
        #pragma unroll
        for (int nt = 0; nt < 4; ++nt) {
            const half8 bf = wf[(nt * 4 + ks) * 64 + lane];
            acc[nt] = __builtin_amdgcn_mfma_f32_16x16x32_f16(af, bf, acc[nt], 0, 0, 0);
        }
    }
    #pragma unroll
    for (int nt = 0; nt < 4; ++nt) {
        #pragma unroll
        for (int reg = 0; reg < 4; ++reg) {
            int node = bn + wv * 16 + ((lane >> 4) << 2) + reg;
            int dim  = nt * 16 + (lane & 15);
            if (node < N_NODES) h2h[(size_t)node * 64 + dim] = __float2half(acc[nt][reg]);
        }
    }
}

// ---------------------------------------------------------------------------
// Gather layer 2, 8-edge-parallel, packed fp16 accumulation, inline weights.
// Pads carry srcs = -1 -> w = 0. Output stored fp16.
// ---------------------------------------------------------------------------
__global__ void __launch_bounds__(256) k_gather2(
    const int* __restrict__ srcs, const int* __restrict__ rowptr,
    const float* __restrict__ as2, const float* __restrict__ ad2,
    const _Float16* __restrict__ h2h, const float* __restrict__ b2,
    __half* __restrict__ out2h)
{
    const int tid  = threadIdx.x;
    const int n    = blockIdx.x * 4 + (tid >> 6);   // N_NODES % 4 == 0
    const int lane = tid & 63;
    const int eg   = lane >> 3;
    const int dq   = lane & 7;
    const int beg = rowptr[n], end = rowptr[n + 1];
    const float adv = ad2[n];

    half8 hacc = {0, 0, 0, 0, 0, 0, 0, 0};
    float wsum = 0.f;
    for (int j = beg + eg; j < end; j += 8) {
        const int s = srcs[j];
        const int sa = (s >= 0) ? s : 0;
        float w = 0.f;
        if (s >= 0) w = __expf(lrelu(as2[s] + adv));
        const half8 v = *(const half8*)&h2h[(size_t)sa * 64 + dq * 8];
        const _Float16 wh = (_Float16)w;
        const half8 ws8 = {wh, wh, wh, wh, wh, wh, wh, wh};
        hacc += v * ws8;                  // 4x v_pk_fma_f16
        wsum += w;
    }
    float a0 = (float)hacc[0], a1 = (float)hacc[1], a2 = (float)hacc[2], a3 = (float)hacc[3];
    float a4 = (float)hacc[4], a5 = (float)hacc[5], a6 = (float)hacc[6], a7 = (float)hacc[7];
    #pragma unroll
    for (int off = 8; off < 64; off <<= 1) {
        a0 += __shfl_xor(a0, off, 64);
        a1 += __shfl_xor(a1, off, 64);
        a2 += __shfl_xor(a2, off, 64);
        a3 += __shfl_xor(a3, off, 64);
        a4 += __shfl_xor(a4, off, 64);
        a5 += __shfl_xor(a5, off, 64);
        a6 += __shfl_xor(a6, off, 64);
        a7 += __shfl_xor(a7, off, 64);
        wsum += __shfl_xor(wsum, off, 64);
    }
    if (eg == 0) {
        const float inv = 1.f / wsum;
        const float4 bA = ((const float4*)b2)[dq * 2];
        const float4 bB = ((const float4*)b2)[dq * 2 + 1];
        __half2 p0 = __floats2half2_rn(elu_f(a0 * inv + bA.x), elu_f(a1 * inv + bA.y));
        __half2 p1 = __floats2half2_rn(elu_f(a2 * inv + bA.z), elu_f(a3 * inv + bA.w));
        __half2 p2 = __floats2half2_rn(elu_f(a4 * inv + bB.x), elu_f(a5 * inv + bB.y));
        __half2 p3 = __floats2half2_rn(elu_f(a6 * inv + bB.z), elu_f(a7 * inv + bB.w));
        uint4 pk;
        pk.x = *(unsigned int*)&p0; pk.y = *(unsigned int*)&p1;
        pk.z = *(unsigned int*)&p2; pk.w = *(unsigned int*)&p3;
        *(uint4*)&out2h[(size_t)n * 64 + dq * 8] = pk;
    }
}

// ---------------------------------------------------------------------------
// Global mean pool: batch sorted -> register runs, flush at boundaries.
// cnt precomputed in k_preall (binary search), so only pool sums here.
// ---------------------------------------------------------------------------
__global__ void __launch_bounds__(256) k_pool(
    const __half* __restrict__ out2h, const int* __restrict__ batch,
    float* __restrict__ pool)
{
    const int wv = threadIdx.x >> 6, d = threadIdx.x & 63;
    const int wid = blockIdx.x * 4 + wv;
    const int per = (N_NODES + 2047) / 2048;
    int n0 = wid * per, n1 = min(n0 + per, N_NODES);
    if (n0 >= n1) return;
    float acc = 0.f; int g = batch[n0];
    for (int n = n0; n < n1; ++n) {
        int gn = batch[n];
        if (gn != g) {
            atomicAdd(&pool[g * 64 + d], acc);
            acc = 0.f; g = gn;
        }
        acc += __half2float(out2h[(size_t)n * 64 + d]);
    }
    atomicAdd(&pool[g * 64 + d], acc);
}

__global__ void k_head(const float* __restrict__ pool, const float* __restrict__ cnt,
                       const float* __restrict__ wp, const float* __restrict__ bp,
                       float* __restrict__ out)
{
    int t = threadIdx.x;
    int g = t >> 4, s = t & 15;
    float c = cnt[g]; if (c < 1.f) c = 1.f;
    float acc = bp[s];
    for (int d = 0; d < 64; ++d) acc += (pool[g * 64 + d] / c) * wp[s * 64 + d];
    out[g * 16 + s] = acc;
}

extern "C" void kernel_launch(void* const* d_in, const int* in_sizes, int n_in,
                              void* d_out, int out_size, void* d_ws, size_t ws_size,
                              hipStream_t stream)
{
    const float* x     = (const float*)d_in[0];
    const int*   ei    = (const int*)  d_in[1];
    const int*   batch = (const int*)  d_in[2];
    const float* w1    = (const float*)d_in[3];
    const float* asr1  = (const float*)d_in[4];
    const float* adr1  = (const float*)d_in[5];
    const float* b1    = (const float*)d_in[6];
    const float* w2    = (const float*)d_in[7];
    const float* asr2  = (const float*)d_in[8];
    const float* adr2  = (const float*)d_in[9];
    const float* b2    = (const float*)d_in[10];
    const float* wp    = (const float*)d_in[11];
    const float* bp    = (const float*)d_in[12];
    float* out = (float*)d_out;

    // Workspace layout (~45 MB)
    float4* agg0 = (float4*)d_ws;                          // N
    float4* agg1 = agg0 + N_NODES;                         // N
    float2* wsA  = (float2*)(agg1 + N_NODES);              // N
    __half* h2h  = (__half*)(wsA + N_NODES);               // N*64 fp16 (16B-aligned)
    __half* out2h = h2h + (size_t)N_NODES * 64;            // N*64 fp16 (16B-aligned)
    float* as2   = (float*)(out2h + (size_t)N_NODES * 64); // N
    float* ad2   = as2 + N_NODES;                          // N
    float* pool  = ad2 + N_NODES;                          // 64*64
    float* cnt   = pool + N_GRAPHS * 64;                   // 64
    int* deg     = (int*)(cnt + N_GRAPHS);                 // N
    int* rowptr  = deg + N_NODES;                          // N+1
    unsigned int* bucketed = (unsigned int*)(rowptr + N_NODES + 1); // E_TOT
    int* srcs    = (int*)(bucketed + E_TOT);               // E_CAP
    int* blockoff    = srcs + E_CAP;                       // NBLKS*NBUCK
    int* bucketCount = blockoff + NBLKS * NBUCK;           // NBUCK
    int* bucketStart = bucketCount + NBUCK;                // NBUCK
    int* bucketPad   = bucketStart + NBUCK;                // NBUCK
    float* A1    = (float*)(bucketPad + NBUCK);            // 8
    float* D1    = A1 + 8;                                 // 8
    float* B2    = D1 + 8;                                 // 128
    float* E2    = B2 + 128;                               // 128
    __half* w2frag = (__half*)(((uintptr_t)(E2 + 128) + 15) & ~(uintptr_t)15); // 8192 fp16

    // Folded projections + fragment W2 + zero bucketCount/pool + cnt (merged)
    k_preall<<<33, 256, 0, stream>>>(w1, asr1, adr1, w2, asr2, adr2,
                                     A1, D1, B2, E2, w2frag, bucketCount, pool,
                                     batch, cnt);

    // Counting-sort CSR build (padded x8, pad sentinel -1, scans fused)
    k_bin1 <<<NBLKS, 256, 0, stream>>>(ei, bucketCount, blockoff);
    k_bin2 <<<NBLKS, 256, 0, stream>>>(ei, bucketCount, blockoff, bucketStart, bucketed);
    k_bhist<<<NBUCK, 256, 0, stream>>>(bucketed, bucketStart, bucketCount, deg, rowptr, bucketPad);
    k_bscat<<<NBUCK, 256, 0, stream>>>(bucketed, bucketStart, bucketCount, bucketPad,
                                       rowptr, srcs);

    // Layer-1 aggregation in x-space
    const int gb = (N_NODES + 15) / 16;
    k_gather1x<<<gb, 256, 0, stream>>>(srcs, rowptr, deg, x, A1, D1, agg0, agg1, wsA);

    // Fused out1-build + as2/ad2 + layer-2 GEMM (MFMA)
    k_h2f<<<(N_NODES + H2_NPB - 1) / H2_NPB, 256, 0, stream>>>(
        agg0, agg1, wsA, w1, b1, w2frag, B2, E2, h2h, as2, ad2);

    // Layer-2 aggregate with inline weights, fp16 output
    k_gather2<<<N_NODES / 4, 256, 0, stream>>>(srcs, rowptr, as2, ad2,
                                               (const _Float16*)h2h, b2, out2h);

    // Mean pool + head
    k_pool<<<512, 256, 0, stream>>>(out2h, batch, pool);
    k_head<<<1, 1024, 0, stream>>>(pool, cnt, wp, bp, out);
}

// Round 17
// 192.588 us; speedup vs baseline: 1.5084x; 1.0156x over previous
//
#include <hip/hip_runtime.h>
#include <hip/hip_fp16.h>

#define N_NODES  100000
#define N_EDGES  1000000
#define E_TOT    1100000   // edges + self-loops
#define E_CAP    1900000   // >= E_TOT + NBUCK*BSLACK = 1,802,464
#define N_GRAPHS 64

// counting-sort CSR parameters
#define BSH    9
#define BSIZE  512                                   // nodes per bucket
#define NBUCK  ((N_NODES + BSIZE - 1) / BSIZE)       // 196
#define CHUNK  4096
#define NBLKS  ((E_TOT + CHUNK - 1) / CHUNK)         // 269
#define BSLACK (7 * BSIZE)                           // fixed per-bucket pad slack
#define EBUF   8192                                  // LDS staging capacity (edges)

typedef _Float16 half8 __attribute__((ext_vector_type(8)));
typedef float    f32x4 __attribute__((ext_vector_type(4)));

__device__ __forceinline__ float elu_f(float v) {
    return v > 0.f ? v : expm1f(v);
}

__device__ __forceinline__ float lrelu(float v) {
    return v > 0.f ? v : 0.2f * v;
}

__device__ __forceinline__ int lbound(const int* __restrict__ a, int n, int v) {
    int lo = 0, hi = n;
    while (lo < hi) { int m = (lo + hi) >> 1; if (a[m] < v) lo = m + 1; else hi = m; }
    return lo;
}

// ---------------------------------------------------------------------------
// k_preall: block 0 = folded attention projections + zero bucketCount +
//           cnt[g] via binary search on sorted batch;
//           blocks 1..32 = fragment-ordered fp16 W2 (+ zero pool).
// ---------------------------------------------------------------------------
__global__ void k_preall(const float* __restrict__ w1,
                         const float* __restrict__ as1v, const float* __restrict__ ad1v,
                         const float* __restrict__ w2,
                         const float* __restrict__ as2v, const float* __restrict__ ad2v,
                         float* __restrict__ A1, float* __restrict__ D1,
                         float* __restrict__ B2, float* __restrict__ E2,
                         __half* __restrict__ w2frag,
                         int* __restrict__ bucketCount, float* __restrict__ pool,
                         const int* __restrict__ batch, float* __restrict__ cnt)
{
    if (blockIdx.x == 0) {
        int t = threadIdx.x;
        if (t < 128) {
            float acc = 0.f;
            for (int d = 0; d < 64; ++d) acc += w2[d * 128 + t] * as2v[d];
            B2[t] = acc;
        } else {
            int k = t - 128;
            float acc = 0.f;
            for (int d = 0; d < 64; ++d) acc += w2[d * 128 + k] * ad2v[d];
            E2[k] = acc;
        }
        if (t < 8) {
            int h = t >> 2, k = t & 3;
            float acc = 0.f;
            for (int d = 0; d < 64; ++d) acc += w1[(h * 64 + d) * 4 + k] * as1v[h * 64 + d];
            A1[t] = acc;
        } else if (t < 16) {
            int i = t - 8, h = i >> 2, k = i & 3;
            float acc = 0.f;
            for (int d = 0; d < 64; ++d) acc += w1[(h * 64 + d) * 4 + k] * ad1v[h * 64 + d];
            D1[i] = acc;
        }
        if (t < NBUCK) bucketCount[t] = 0;
        if (t < N_GRAPHS) {
            int a = lbound(batch, N_NODES, t);
            int b = lbound(batch, N_NODES, t + 1);
            cnt[t] = (float)(b - a);
        }
    } else {
        int f = (blockIdx.x - 1) * 256 + threadIdx.x;  // 8192 total
        int j = f & 7, ln = (f >> 3) & 63, g = f >> 9; // g = nt*4+ks
        int nt = g >> 2, ks = g & 3;
        int col = nt * 16 + (ln & 15);
        int k   = ks * 32 + ((ln >> 4) << 3) + j;
        w2frag[f] = __float2half(w2[col * 128 + k]);
        if (f < N_GRAPHS * 64) pool[f] = 0.f;          // pool only; cnt written above
    }
}

// ---------------------------------------------------------------------------
// Counting-sort CSR build — no per-edge global atomics, 3 kernels.
// P1: per-block LDS bucket histogram; reserve per-(block,bucket) offsets.
// ---------------------------------------------------------------------------
__global__ void __launch_bounds__(256) k_bin1(
    const int* __restrict__ ei, int* __restrict__ bucketCount, int* __restrict__ blockoff)
{
    __shared__ int hist[NBUCK];
    const int t = threadIdx.x;
    for (int i = t; i < NBUCK; i += 256) hist[i] = 0;
    __syncthreads();
    const int e0 = blockIdx.x * CHUNK;
    for (int i = t; i < CHUNK; i += 256) {
        int e = e0 + i;
        if (e < E_TOT) {
            int dst = (e < N_EDGES) ? ei[N_EDGES + e] : (e - N_EDGES);
            atomicAdd(&hist[dst >> BSH], 1);
        }
    }
    __syncthreads();
    for (int i = t; i < NBUCK; i += 256)
        blockoff[blockIdx.x * NBUCK + i] = atomicAdd(&bucketCount[i], hist[i]);
}

// P2 (scan fused): each block scans bucketCount in LDS; block 0 also
// materializes bucketStart. Then scatter packed keys into bucket regions.
__global__ void __launch_bounds__(256) k_bin2(
    const int* __restrict__ ei, const int* __restrict__ bucketCount,
    const int* __restrict__ blockoff, int* __restrict__ bucketStart,
    unsigned int* __restrict__ bucketed)
{
    __shared__ int sh[256];
    __shared__ int cur[NBUCK];
    const int t = threadIdx.x;
    int v = (t < NBUCK) ? bucketCount[t] : 0;
    int acc = v;
    sh[t] = acc; __syncthreads();
    for (int off = 1; off < 256; off <<= 1) {
        int add = (t >= off) ? sh[t - off] : 0;
        __syncthreads();
        acc += add; sh[t] = acc; __syncthreads();
    }
    if (t < NBUCK) {
        int st = acc - v;                               // exclusive
        cur[t] = st + blockoff[blockIdx.x * NBUCK + t];
        if (blockIdx.x == 0) bucketStart[t] = st;
    }
    __syncthreads();
    const int e0 = blockIdx.x * CHUNK;
    for (int i = t; i < CHUNK; i += 256) {
        int e = e0 + i;
        if (e < E_TOT) {
            int src = (e < N_EDGES) ? ei[e] : (e - N_EDGES);
            int dst = (e < N_EDGES) ? ei[N_EDGES + e] : (e - N_EDGES);
            int b = dst >> BSH;
            int p = atomicAdd(&cur[b], 1);
            bucketed[p] = (unsigned)src | ((unsigned)(dst & (BSIZE - 1)) << 17);
        }
    }
}

// P3 (merged bhist+bscat): fully bucket-local since base_b is a closed form:
//   base_b = bucketStart[b] + BSLACK*b   (fixed per-bucket slack)
// histogram -> deg; padded local scan -> rowptr; cursors -> scatter srcs;
// per-row pad fill with -1. Bucket edges staged in LDS (global fallback).
__global__ void __launch_bounds__(256) k_bcsr(
    const unsigned int* __restrict__ bucketed,
    const int* __restrict__ bucketStart, const int* __restrict__ bucketCount,
    int* __restrict__ deg, int* __restrict__ rowptr, int* __restrict__ srcs)
{
    __shared__ int hist[BSIZE];
    __shared__ int sh[256];
    __shared__ int cur[BSIZE];
    __shared__ unsigned ebuf[EBUF];
    const int t = threadIdx.x;
    const int b = blockIdx.x;
    const int beg = bucketStart[b], cnt = bucketCount[b];
    const int base = beg + BSLACK * b;
    const bool lds = (cnt <= EBUF);

    hist[t] = 0; hist[t + 256] = 0;
    __syncthreads();
    if (lds) {
        for (int i = t; i < cnt; i += 256) {
            unsigned p = bucketed[beg + i];
            ebuf[i] = p;
            atomicAdd(&hist[p >> 17], 1);
        }
    } else {
        for (int i = t; i < cnt; i += 256)
            atomicAdd(&hist[bucketed[beg + i] >> 17], 1);
    }
    __syncthreads();

    int h0 = hist[2 * t], h1 = hist[2 * t + 1];
    int a = (h0 + 7) & ~7, c = (h1 + 7) & ~7;
    int s = a + c;
    sh[t] = s; __syncthreads();
    for (int off = 1; off < 256; off <<= 1) {
        int add = (t >= off) ? sh[t - off] : 0;
        __syncthreads();
        s += add; sh[t] = s; __syncthreads();
    }
    int lb = s - a - c;                    // exclusive padded prefix before node 2t
    const int n0 = b * BSIZE;
    int na = n0 + 2 * t, nb = n0 + 2 * t + 1;
    if (na < N_NODES) { deg[na] = h0; rowptr[na] = base + lb;     cur[2 * t]     = base + lb; }
    if (nb < N_NODES) { deg[nb] = h1; rowptr[nb] = base + lb + a; cur[2 * t + 1] = base + lb + a; }
    __syncthreads();

    for (int i = t; i < cnt; i += 256) {
        unsigned p = lds ? ebuf[i] : bucketed[beg + i];
        int rank = atomicAdd(&cur[p >> 17], 1);
        srcs[rank] = (int)(p & 0x1FFFFu);
    }
    __syncthreads();

    // per-row pad fill: cur[nl] == rowptr[n] + deg[n] after scatter
    #pragma unroll
    for (int k = 0; k < 2; ++k) {
        int nl = t + k * 256;
        int n = n0 + nl;
        if (n < N_NODES) {
            int d  = (nl & 1) ? hist[nl] : hist[nl];   // hist[nl] holds deg
            int e  = cur[nl] + (((d + 7) & ~7) - d);   // pad8 end
            for (int j = cur[nl]; j < e; ++j) srcs[j] = -1;
        }
    }
}

// ---------------------------------------------------------------------------
// Layer-1 aggregation in x-space (16 lanes per node, one edge per lane)
// ---------------------------------------------------------------------------
__global__ void __launch_bounds__(256) k_gather1x(
    const int* __restrict__ srcs, const int* __restrict__ rowptr, const int* __restrict__ deg,
    const float* __restrict__ x,
    const float* __restrict__ A1c, const float* __restrict__ D1c,
    float4* __restrict__ agg0, float4* __restrict__ agg1, float2* __restrict__ wsA)
{
    const int tid  = threadIdx.x;
    const int n    = blockIdx.x * 16 + (tid >> 4);
    const int lane = tid & 15;
    if (n >= N_NODES) return;

    const float4 A0 = ((const float4*)A1c)[0], A1v = ((const float4*)A1c)[1];
    const float4 D0 = ((const float4*)D1c)[0], D1v = ((const float4*)D1c)[1];
    const float4 xn = ((const float4*)x)[n];
    const float ad0 = xn.x * D0.x + xn.y * D0.y + xn.z * D0.z + xn.w * D0.w;
    const float ad1 = xn.x * D1v.x + xn.y * D1v.y + xn.z * D1v.z + xn.w * D1v.w;

    const int beg = rowptr[n], rend = beg + deg[n];
    float4 acc0 = {0.f, 0.f, 0.f, 0.f}, acc1 = {0.f, 0.f, 0.f, 0.f};
    float ws0 = 0.f, ws1 = 0.f;
    for (int j = beg + lane; j < rend; j += 16) {
        const int s = srcs[j];
        const float4 xs = ((const float4*)x)[s];
        const float as0 = xs.x * A0.x + xs.y * A0.y + xs.z * A0.z + xs.w * A0.w;
        const float as1 = xs.x * A1v.x + xs.y * A1v.y + xs.z * A1v.z + xs.w * A1v.w;
        const float w0 = __expf(lrelu(as0 + ad0));
        const float w1 = __expf(lrelu(as1 + ad1));
        acc0.x = fmaf(w0, xs.x, acc0.x); acc0.y = fmaf(w0, xs.y, acc0.y);
        acc0.z = fmaf(w0, xs.z, acc0.z); acc0.w = fmaf(w0, xs.w, acc0.w);
        acc1.x = fmaf(w1, xs.x, acc1.x); acc1.y = fmaf(w1, xs.y, acc1.y);
        acc1.z = fmaf(w1, xs.z, acc1.z); acc1.w = fmaf(w1, xs.w, acc1.w);
        ws0 += w0; ws1 += w1;
    }
    #pragma unroll
    for (int off = 1; off < 16; off <<= 1) {
        acc0.x += __shfl_xor(acc0.x, off, 64);
        acc0.y += __shfl_xor(acc0.y, off, 64);
        acc0.z += __shfl_xor(acc0.z, off, 64);
        acc0.w += __shfl_xor(acc0.w, off, 64);
        acc1.x += __shfl_xor(acc1.x, off, 64);
        acc1.y += __shfl_xor(acc1.y, off, 64);
        acc1.z += __shfl_xor(acc1.z, off, 64);
        acc1.w += __shfl_xor(acc1.w, off, 64);
        ws0    += __shfl_xor(ws0,    off, 64);
        ws1    += __shfl_xor(ws1,    off, 64);
    }
    if (lane == 0) {
        agg0[n] = acc0;
        agg1[n] = acc1;
        wsA[n]  = make_float2(ws0, ws1);
    }
}

// ---------------------------------------------------------------------------
// k_h2f: out1 built as fp16 in LDS, as2/ad2 reduction, MFMA GEMM -> h2 fp16
// ---------------------------------------------------------------------------
#define H2_NPB 64
#define SROW_H_LD 136
__global__ void __launch_bounds__(256) k_h2f(
    const float4* __restrict__ agg0, const float4* __restrict__ agg1,
    const float2* __restrict__ wsA,
    const float* __restrict__ w1, const float* __restrict__ b1,
    const __half* __restrict__ w2frag,
    const float* __restrict__ B2, const float* __restrict__ E2,
    __half* __restrict__ h2h, float* __restrict__ as2, float* __restrict__ ad2)
{
    __shared__ __align__(16) _Float16 srow[H2_NPB * SROW_H_LD];
    const int tid = threadIdx.x;
    const int bn  = blockIdx.x * H2_NPB;

    #pragma unroll 4
    for (int t = 0; t < 16; ++t) {
        int i = tid + t * 256;
        int r = i >> 6, c2 = i & 63;
        int n = bn + r;
        int head = c2 >> 5;
        float4 a; float ws;
        if (n < N_NODES) {
            a = head ? agg1[n] : agg0[n];
            float2 w = wsA[n];
            ws = head ? w.y : w.x;
        } else { a = make_float4(0.f, 0.f, 0.f, 0.f); ws = 1.f; }
        const float4 wA = ((const float4*)w1)[2 * c2];
        const float4 wB = ((const float4*)w1)[2 * c2 + 1];
        const float2 bb = ((const float2*)b1)[c2];
        float inv = 1.f / ws;
        float v0 = elu_f((a.x * wA.x + a.y * wA.y + a.z * wA.z + a.w * wA.w) * inv + bb.x);
        float v1 = elu_f((a.x * wB.x + a.y * wB.y + a.z * wB.z + a.w * wB.w) * inv + bb.y);
        *(__half2*)&srow[r * SROW_H_LD + 2 * c2] = __floats2half2_rn(v0, v1);
    }
    __syncthreads();

    {
        int r = tid >> 2, q = tid & 3;
        const __half2* row = (const __half2*)&srow[r * SROW_H_LD];
        float ps = 0.f, pd = 0.f;
        #pragma unroll 4
        for (int i = 0; i < 16; ++i) {
            int c2 = q * 16 + i;
            float2 v  = __half22float2(row[c2]);
            float2 Bv = ((const float2*)B2)[c2];
            float2 Ev = ((const float2*)E2)[c2];
            ps += v.x * Bv.x + v.y * Bv.y;
            pd += v.x * Ev.x + v.y * Ev.y;
        }
        ps += __shfl_xor(ps, 1, 64); ps += __shfl_xor(ps, 2, 64);
        pd += __shfl_xor(pd, 1, 64); pd += __shfl_xor(pd, 2, 64);
        int n = bn + r;
        if (q == 0 && n < N_NODES) { as2[n] = ps; ad2[n] = pd; }
    }

    const int lane = tid & 63;
    const int wv   = tid >> 6;
    const int mrow = lane & 15;
    const int kc   = lane >> 4;
    f32x4 acc[4] = {{0.f,0.f,0.f,0.f},{0.f,0.f,0.f,0.f},{0.f,0.f,0.f,0.f},{0.f,0.f,0.f,0.f}};
    const half8* __restrict__ wf = (const half8*)w2frag;
    #pragma unroll
    for (int ks = 0; ks < 4; ++ks) {
        const half8 af = *(const half8*)&srow[(wv * 16 + mrow) * SROW_H_LD + ks * 32 + kc * 8];
        #pragma unroll
        for (int nt = 0; nt < 4; ++nt) {
            const half8 bf = wf[(nt * 4 + ks) * 64 + lane];
            acc[nt] = __builtin_amdgcn_mfma_f32_16x16x32_f16(af, bf, acc[nt], 0, 0, 0);
        }
    }
    #pragma unroll
    for (int nt = 0; nt < 4; ++nt) {
        #pragma unroll
        for (int reg = 0; reg < 4; ++reg) {
            int node = bn + wv * 16 + ((lane >> 4) << 2) + reg;
            int dim  = nt * 16 + (lane & 15);
            if (node < N_NODES) h2h[(size_t)node * 64 + dim] = __float2half(acc[nt][reg]);
        }
    }
}

// ---------------------------------------------------------------------------
// Gather layer 2, 8-edge-parallel, packed fp16 accumulation, inline weights.
// Row end = rowptr[n] + pad8(deg[n]) (bucket-slack regions never touched).
// Pads carry srcs = -1 -> w = 0. Output stored fp16.
// ---------------------------------------------------------------------------
__global__ void __launch_bounds__(256) k_gather2(
    const int* __restrict__ srcs, const int* __restrict__ rowptr, const int* __restrict__ deg,
    const float* __restrict__ as2, const float* __restrict__ ad2,
    const _Float16* __restrict__ h2h, const float* __restrict__ b2,
    __half* __restrict__ out2h)
{
    const int tid  = threadIdx.x;
    const int n    = blockIdx.x * 4 + (tid >> 6);   // N_NODES % 4 == 0
    const int lane = tid & 63;
    const int eg   = lane >> 3;
    const int dq   = lane & 7;
    const int beg = rowptr[n];
    const int end = beg + ((deg[n] + 7) & ~7);
    const float adv = ad2[n];

    half8 hacc = {0, 0, 0, 0, 0, 0, 0, 0};
    float wsum = 0.f;
    for (int j = beg + eg; j < end; j += 8) {
        const int s = srcs[j];
        const int sa = (s >= 0) ? s : 0;
        float w = 0.f;
        if (s >= 0) w = __expf(lrelu(as2[s] + adv));
        const half8 v = *(const half8*)&h2h[(size_t)sa * 64 + dq * 8];
        const _Float16 wh = (_Float16)w;
        const half8 ws8 = {wh, wh, wh, wh, wh, wh, wh, wh};
        hacc += v * ws8;                  // 4x v_pk_fma_f16
        wsum += w;
    }
    float a0 = (float)hacc[0], a1 = (float)hacc[1], a2 = (float)hacc[2], a3 = (float)hacc[3];
    float a4 = (float)hacc[4], a5 = (float)hacc[5], a6 = (float)hacc[6], a7 = (float)hacc[7];
    #pragma unroll
    for (int off = 8; off < 64; off <<= 1) {
        a0 += __shfl_xor(a0, off, 64);
        a1 += __shfl_xor(a1, off, 64);
        a2 += __shfl_xor(a2, off, 64);
        a3 += __shfl_xor(a3, off, 64);
        a4 += __shfl_xor(a4, off, 64);
        a5 += __shfl_xor(a5, off, 64);
        a6 += __shfl_xor(a6, off, 64);
        a7 += __shfl_xor(a7, off, 64);
        wsum += __shfl_xor(wsum, off, 64);
    }
    if (eg == 0) {
        const float inv = 1.f / wsum;
        const float4 bA = ((const float4*)b2)[dq * 2];
        const float4 bB = ((const float4*)b2)[dq * 2 + 1];
        __half2 p0 = __floats2half2_rn(elu_f(a0 * inv + bA.x), elu_f(a1 * inv + bA.y));
        __half2 p1 = __floats2half2_rn(elu_f(a2 * inv + bA.z), elu_f(a3 * inv + bA.w));
        __half2 p2 = __floats2half2_rn(elu_f(a4 * inv + bB.x), elu_f(a5 * inv + bB.y));
        __half2 p3 = __floats2half2_rn(elu_f(a6 * inv + bB.z), elu_f(a7 * inv + bB.w));
        uint4 pk;
        pk.x = *(unsigned int*)&p0; pk.y = *(unsigned int*)&p1;
        pk.z = *(unsigned int*)&p2; pk.w = *(unsigned int*)&p3;
        *(uint4*)&out2h[(size_t)n * 64 + dq * 8] = pk;
    }
}

// ---------------------------------------------------------------------------
// Global mean pool: batch sorted -> register runs, flush at boundaries.
// ---------------------------------------------------------------------------
__global__ void __launch_bounds__(256) k_pool(
    const __half* __restrict__ out2h, const int* __restrict__ batch,
    float* __restrict__ pool)
{
    const int wv = threadIdx.x >> 6, d = threadIdx.x & 63;
    const int wid = blockIdx.x * 4 + wv;
    const int per = (N_NODES + 2047) / 2048;
    int n0 = wid * per, n1 = min(n0 + per, N_NODES);
    if (n0 >= n1) return;
    float acc = 0.f; int g = batch[n0];
    for (int n = n0; n < n1; ++n) {
        int gn = batch[n];
        if (gn != g) {
            atomicAdd(&pool[g * 64 + d], acc);
            acc = 0.f; g = gn;
        }
        acc += __half2float(out2h[(size_t)n * 64 + d]);
    }
    atomicAdd(&pool[g * 64 + d], acc);
}

__global__ void k_head(const float* __restrict__ pool, const float* __restrict__ cnt,
                       const float* __restrict__ wp, const float* __restrict__ bp,
                       float* __restrict__ out)
{
    int t = threadIdx.x;
    int g = t >> 4, s = t & 15;
    float c = cnt[g]; if (c < 1.f) c = 1.f;
    float acc = bp[s];
    for (int d = 0; d < 64; ++d) acc += (pool[g * 64 + d] / c) * wp[s * 64 + d];
    out[g * 16 + s] = acc;
}

extern "C" void kernel_launch(void* const* d_in, const int* in_sizes, int n_in,
                              void* d_out, int out_size, void* d_ws, size_t ws_size,
                              hipStream_t stream)
{
    const float* x     = (const float*)d_in[0];
    const int*   ei    = (const int*)  d_in[1];
    const int*   batch = (const int*)  d_in[2];
    const float* w1    = (const float*)d_in[3];
    const float* asr1  = (const float*)d_in[4];
    const float* adr1  = (const float*)d_in[5];
    const float* b1    = (const float*)d_in[6];
    const float* w2    = (const float*)d_in[7];
    const float* asr2  = (const float*)d_in[8];
    const float* adr2  = (const float*)d_in[9];
    const float* b2    = (const float*)d_in[10];
    const float* wp    = (const float*)d_in[11];
    const float* bp    = (const float*)d_in[12];
    float* out = (float*)d_out;

    // Workspace layout (~45 MB)
    float4* agg0 = (float4*)d_ws;                          // N
    float4* agg1 = agg0 + N_NODES;                         // N
    float2* wsA  = (float2*)(agg1 + N_NODES);              // N
    __half* h2h  = (__half*)(wsA + N_NODES);               // N*64 fp16 (16B-aligned)
    __half* out2h = h2h + (size_t)N_NODES * 64;            // N*64 fp16 (16B-aligned)
    float* as2   = (float*)(out2h + (size_t)N_NODES * 64); // N
    float* ad2   = as2 + N_NODES;                          // N
    float* pool  = ad2 + N_NODES;                          // 64*64
    float* cnt   = pool + N_GRAPHS * 64;                   // 64
    int* deg     = (int*)(cnt + N_GRAPHS);                 // N
    int* rowptr  = deg + N_NODES;                          // N
    unsigned int* bucketed = (unsigned int*)(rowptr + N_NODES); // E_TOT
    int* srcs    = (int*)(bucketed + E_TOT);               // E_CAP
    int* blockoff    = srcs + E_CAP;                       // NBLKS*NBUCK
    int* bucketCount = blockoff + NBLKS * NBUCK;           // NBUCK
    int* bucketStart = bucketCount + NBUCK;                // NBUCK
    float* A1    = (float*)(bucketStart + NBUCK);          // 8
    float* D1    = A1 + 8;                                 // 8
    float* B2    = D1 + 8;                                 // 128
    float* E2    = B2 + 128;                               // 128
    __half* w2frag = (__half*)(((uintptr_t)(E2 + 128) + 15) & ~(uintptr_t)15); // 8192 fp16

    // Folded projections + fragment W2 + zero bucketCount/pool + cnt (merged)
    k_preall<<<33, 256, 0, stream>>>(w1, asr1, adr1, w2, asr2, adr2,
                                     A1, D1, B2, E2, w2frag, bucketCount, pool,
                                     batch, cnt);

    // Counting-sort CSR build: 3 kernels, fixed-slack bucket bases
    k_bin1<<<NBLKS, 256, 0, stream>>>(ei, bucketCount, blockoff);
    k_bin2<<<NBLKS, 256, 0, stream>>>(ei, bucketCount, blockoff, bucketStart, bucketed);
    k_bcsr<<<NBUCK, 256, 0, stream>>>(bucketed, bucketStart, bucketCount, deg, rowptr, srcs);

    // Layer-1 aggregation in x-space
    const int gb = (N_NODES + 15) / 16;
    k_gather1x<<<gb, 256, 0, stream>>>(srcs, rowptr, deg, x, A1, D1, agg0, agg1, wsA);

    // Fused out1-build + as2/ad2 + layer-2 GEMM (MFMA)
    k_h2f<<<(N_NODES + H2_NPB - 1) / H2_NPB, 256, 0, stream>>>(
        agg0, agg1, wsA, w1, b1, w2frag, B2, E2, h2h, as2, ad2);

    // Layer-2 aggregate with inline weights, fp16 output
    k_gather2<<<N_NODES / 4, 256, 0, stream>>>(srcs, rowptr, deg, as2, ad2,
                                               (const _Float16*)h2h, b2, out2h);

    // Mean pool + head
    k_pool<<<512, 256, 0, stream>>>(out2h, batch, pool);
    k_head<<<1, 1024, 0, stream>>>(pool, cnt, wp, bp, out);
}